// Round 3
// baseline (604.969 us; speedup 1.0000x reference)
//
#include <hip/hip_runtime.h>
#include <hip/hip_bf16.h>

#define MIN_NORM 1e-15f
#define EPS 1e-7f
#define MAX_NORM 1000.0f

#define NN 30000
#define PP 4
#define DD 64
#define EE 480000

__device__ inline float frcp(float x) { return __builtin_amdgcn_rcpf(x); }
__device__ inline float bf2f(unsigned short u) { return __uint_as_float(((unsigned)u) << 16); }
__device__ inline unsigned short f2bf(float f) {
    unsigned u = __float_as_uint(f);
    return (unsigned short)((u + 0x7fffu + ((u >> 16) & 1u)) >> 16);
}

// ---------- wave-wide helpers (wave = 64 lanes = one point of D=64) ----------
__device__ inline float wsum(float v) {
#pragma unroll
    for (int off = 32; off >= 1; off >>= 1) v += __shfl_xor(v, off, 64);
    return v;
}
__device__ inline void wsum2(float& a, float& b) {
#pragma unroll
    for (int off = 32; off >= 1; off >>= 1) {
        a += __shfl_xor(a, off, 64);
        b += __shfl_xor(b, off, 64);
    }
}

// expmap0 (K=1) + proj: tangent per-lane (lane0 ignored) -> point per-lane.
__device__ inline float expmap0_proj_pt(float v, int lane) {
    float sp = (lane == 0) ? 0.f : v;
    float n2 = wsum(sp * sp);
    float n = fmaxf(sqrtf(n2), MIN_NORM);
    float ep = __expf(n), em = frcp(ep);
    float s = 0.5f * (ep - em) * frcp(n);
    float time = sqrtf(fmaxf(1.f + s * s * n2, EPS));
    return (lane == 0) ? time : s * sp;
}
// logmap0 (K=1): point per-lane -> tangent per-lane (lane0 = 0).
__device__ inline float logmap0_pt(float x, int lane) {
    float sp = (lane == 0) ? 0.f : x;
    float n2 = wsum(sp * sp);
    float n = fmaxf(sqrtf(n2), MIN_NORM);
    float x0 = __shfl(x, 0, 64);
    float th = fmaxf(x0, 1.f + EPS);
    float ac = __logf(th + sqrtf(fmaxf(th * th - 1.f, MIN_NORM)));
    return (lane == 0) ? 0.f : (ac * sp * frcp(n));
}

// ---------- 16-lane-group reduce ----------
__device__ inline float gsum16(float v) {
#pragma unroll
    for (int off = 8; off >= 1; off >>= 1) v += __shfl_xor(v, off, 64);
    return v;
}

// ---------- pack W: Wt2[(k>>2)*1024 + j*4 + (k&3)] = W[j][k]  (float4 idx (k>>2)*256+j) ----------
__global__ void transpose_kernel(const float* __restrict__ w, float* __restrict__ wt2) {
    int j = blockIdx.x;
    int k = threadIdx.x;
    wt2[(k >> 2) * 1024 + j * 4 + (k & 3)] = w[j * 256 + k];
}

// ---------- fused front: logmap0 -> GEMM -> mobius-add(bias) -> logmap0 -> xt(bf16) ----------
#define GR 16
__global__ __launch_bounds__(256) void fused_front_kernel(const float* __restrict__ x,
                                                          const float* __restrict__ wt2,
                                                          const float* __restrict__ bias,
                                                          unsigned short* __restrict__ xt) {
    __shared__ float ulds[GR * 256];
    int tid = threadIdx.x;
    int lane = tid & 63;
    int p = tid >> 6;
    int row0 = blockIdx.x * GR;

    // prologue: u = logmap0(x) into LDS; time recomputed algebraically (no broadcast)
#pragma unroll 1
    for (int i = 0; i < GR; i++) {
        float xv = x[(size_t)(row0 + i) * 256 + tid];
        float sp = (lane == 0) ? 0.f : xv;
        float n2 = wsum(sp * sp);
        float n = fmaxf(sqrtf(n2), MIN_NORM);
        float th = fmaxf(sqrtf(1.f + n2), 1.f + EPS);
        float ac = __logf(th + sqrtf(fmaxf(th * th - 1.f, MIN_NORM)));
        ulds[i * 256 + tid] = (lane == 0) ? 0.f : ac * sp * frcp(n);
    }

    // hoisted bias tangent (wave p == point p): usp (lane0=0), U2 = ||usp||^2
    float b = bias[p * 64 + lane];
    float y = expmap0_proj_pt(b, lane);
    float usp = logmap0_pt(y, lane);
    float U2 = wsum(usp * usp);

    __syncthreads();

    // GEMM: 2 rows x 8 cols per thread. mu[r][c] = sum_k u[r][k] * W[c][k]
    int rt = tid >> 5;   // 0..7 -> rows 2rt, 2rt+1
    int ct = tid & 31;   // cols 8ct .. 8ct+7
    const float4* U4 = (const float4*)ulds;   // [GR][64]
    const float4* w4 = (const float4*)wt2;    // [64][256]
    float acc0[8], acc1[8];
#pragma unroll
    for (int j = 0; j < 8; j++) { acc0[j] = 0.f; acc1[j] = 0.f; }
#pragma unroll 2
    for (int kc = 0; kc < 64; kc++) {
        float4 u0 = U4[(2 * rt) * 64 + kc];
        float4 u1 = U4[(2 * rt + 1) * 64 + kc];
#pragma unroll
        for (int j = 0; j < 8; j++) {
            float4 wv = w4[kc * 256 + ct * 8 + j];
            acc0[j] = fmaf(u0.x, wv.x, acc0[j]);
            acc0[j] = fmaf(u0.y, wv.y, acc0[j]);
            acc0[j] = fmaf(u0.z, wv.z, acc0[j]);
            acc0[j] = fmaf(u0.w, wv.w, acc0[j]);
            acc1[j] = fmaf(u1.x, wv.x, acc1[j]);
            acc1[j] = fmaf(u1.y, wv.y, acc1[j]);
            acc1[j] = fmaf(u1.z, wv.z, acc1[j]);
            acc1[j] = fmaf(u1.w, wv.w, acc1[j]);
        }
    }
    __syncthreads();
    // write mu back into the same LDS
    float4* M4 = (float4*)ulds;
    M4[(2 * rt) * 64 + ct * 2 + 0] = make_float4(acc0[0], acc0[1], acc0[2], acc0[3]);
    M4[(2 * rt) * 64 + ct * 2 + 1] = make_float4(acc0[4], acc0[5], acc0[6], acc0[7]);
    M4[(2 * rt + 1) * 64 + ct * 2 + 0] = make_float4(acc1[0], acc1[1], acc1[2], acc1[3]);
    M4[(2 * rt + 1) * 64 + ct * 2 + 1] = make_float4(acc1[4], acc1[5], acc1[6], acc1[7]);
    __syncthreads();

    // epilogue: per row, 2 reductions + scalar algebra
#pragma unroll 1
    for (int i = 0; i < GR; i++) {
        float mu = ulds[i * 256 + tid];
        float musp = (lane == 0) ? 0.f : mu;
        float n2 = musp * musp;
        float duu = musp * usp;
        wsum2(n2, duu);

        float n = fmaxf(sqrtf(n2), MIN_NORM);
        float ep = __expf(n), em = frcp(ep);
        float s = 0.5f * (ep - em) * frcp(n);     // sinh(n)/n
        float hs2 = s * s * n2;                    // ||h_sp||^2
        float h0 = sqrtf(fmaxf(1.f + hs2, EPS));   // h time
        float hs = s * musp;                       // h space (lane0=0)

        float yn = fmaxf(s * n, MIN_NORM);         // ||h_sp||
        float dhu = s * duu;                       // <h_sp, usp>
        float alpha = dhu * frcp(yn);
        float g = alpha * (1.f - h0);
        float ux = dhu - g * yn;                   // <h_sp, w_sp>
        float t = ux * frcp(fmaxf(h0, MIN_NORM));
        float w2 = U2 - 2.f * g * alpha + g * g;   // ||w_sp||^2
        float md = w2 - t * t;                     // minkowski dot
        float normu = fminf(sqrtf(fmaxf(md, EPS)), MAX_NORM);
        float theta = fmaxf(normu, MIN_NORM);
        float ep2 = __expf(theta), em2 = frcp(ep2);
        float ch = 0.5f * (ep2 + em2);
        float shot = 0.5f * (ep2 - em2) * frcp(theta);

        float wsp = (lane == 0) ? 0.f : (usp - g * (hs * frcp(yn)));
        float rsp = ch * hs + shot * wsp;          // result space (lane0=0)
        float rn2 = ch * ch * hs2 + 2.f * ch * shot * ux + shot * shot * w2;
        float rtime = sqrtf(fmaxf(1.f + rn2, EPS));

        float th2 = fmaxf(rtime, 1.f + EPS);
        float ac2 = __logf(th2 + sqrtf(fmaxf(th2 * th2 - 1.f, MIN_NORM)));
        float rn = fmaxf(sqrtf(rn2), MIN_NORM);
        float o = ac2 * rsp * frcp(rn);

        xt[(size_t)(row0 + i) * 256 + tid] = f2bf(o);
    }
}

// ---------- CSR build ----------
__global__ void zero_kernel(int* __restrict__ p, int n) {
    int i = blockIdx.x * 256 + threadIdx.x;
    if (i < n) p[i] = 0;
}
__global__ void hist_kernel(const int* __restrict__ row, int* __restrict__ counts, int E) {
    int e = blockIdx.x * 256 + threadIdx.x;
    if (e < E) atomicAdd(&counts[row[e]], 1);
}

#define SCH 30
__global__ __launch_bounds__(1024) void scan_kernel(const int* __restrict__ counts,
                                                    int* __restrict__ starts, int n) {
    int tid = threadIdx.x, lane = tid & 63, wv = tid >> 6;
    int i0 = tid * SCH;
    int c[SCH];
    int s = 0;
#pragma unroll
    for (int j = 0; j < SCH; j++) {
        int idx = i0 + j;
        int v = (idx < n) ? counts[idx] : 0;
        c[j] = v;
        s += v;
    }
    int incl = s;
#pragma unroll
    for (int off = 1; off < 64; off <<= 1) {
        int t = __shfl_up(incl, off, 64);
        if (lane >= off) incl += t;
    }
    __shared__ int wtot[16];
    if (lane == 63) wtot[wv] = incl;
    __syncthreads();
    if (wv == 0 && lane < 16) {
        int v = wtot[lane];
        int sc = v;
#pragma unroll
        for (int off = 1; off < 16; off <<= 1) {
            int t = __shfl_up(sc, off, 64);
            if (lane >= off) sc += t;
        }
        wtot[lane] = sc - v;  // exclusive
    }
    __syncthreads();
    int run = incl - s + wtot[wv];
#pragma unroll
    for (int j = 0; j < SCH; j++) {
        int idx = i0 + j;
        if (idx < n) starts[idx] = run;
        run += c[j];
    }
    if (tid == 1023) starts[n] = run;
}

__global__ void scatter_kernel(const int* __restrict__ row, const int* __restrict__ col,
                               const float* __restrict__ val, const int* __restrict__ starts,
                               int* __restrict__ cursor, int* __restrict__ colp,
                               float* __restrict__ valp, int E) {
    int e = blockIdx.x * 256 + threadIdx.x;
    if (e < E) {
        int r = row[e];
        int pos = starts[r] + atomicAdd(&cursor[r], 1);
        colp[pos] = col[e];
        valp[pos] = val[e];
    }
}

// ---------- SpMM (wave/row, bf16 gather) + fused final chain ----------
__global__ __launch_bounds__(256) void spmm_final_kernel(const unsigned short* __restrict__ xt,
                                                         const int* __restrict__ colp,
                                                         const float* __restrict__ valp,
                                                         const int* __restrict__ starts,
                                                         float4* __restrict__ out4) {
    int w = threadIdx.x >> 6;
    int lane = threadIdx.x & 63;
    int r = blockIdx.x * 4 + w;
    int s = starts[r], e = starts[r + 1];

    float4 acc = {0.f, 0.f, 0.f, 0.f};
    int i = s;
    for (; i + 4 <= e; i += 4) {
        int c0 = colp[i], c1 = colp[i + 1], c2 = colp[i + 2], c3 = colp[i + 3];
        float v0 = valp[i], v1 = valp[i + 1], v2 = valp[i + 2], v3 = valp[i + 3];
        ushort4 a0 = *(const ushort4*)(xt + ((size_t)c0 << 8) + (lane << 2));
        ushort4 a1 = *(const ushort4*)(xt + ((size_t)c1 << 8) + (lane << 2));
        ushort4 a2 = *(const ushort4*)(xt + ((size_t)c2 << 8) + (lane << 2));
        ushort4 a3 = *(const ushort4*)(xt + ((size_t)c3 << 8) + (lane << 2));
        acc.x = fmaf(v0, bf2f(a0.x), acc.x); acc.y = fmaf(v0, bf2f(a0.y), acc.y);
        acc.z = fmaf(v0, bf2f(a0.z), acc.z); acc.w = fmaf(v0, bf2f(a0.w), acc.w);
        acc.x = fmaf(v1, bf2f(a1.x), acc.x); acc.y = fmaf(v1, bf2f(a1.y), acc.y);
        acc.z = fmaf(v1, bf2f(a1.z), acc.z); acc.w = fmaf(v1, bf2f(a1.w), acc.w);
        acc.x = fmaf(v2, bf2f(a2.x), acc.x); acc.y = fmaf(v2, bf2f(a2.y), acc.y);
        acc.z = fmaf(v2, bf2f(a2.z), acc.z); acc.w = fmaf(v2, bf2f(a2.w), acc.w);
        acc.x = fmaf(v3, bf2f(a3.x), acc.x); acc.y = fmaf(v3, bf2f(a3.y), acc.y);
        acc.z = fmaf(v3, bf2f(a3.z), acc.z); acc.w = fmaf(v3, bf2f(a3.w), acc.w);
    }
    for (; i < e; i++) {
        int c0 = colp[i];
        float v0 = valp[i];
        ushort4 a0 = *(const ushort4*)(xt + ((size_t)c0 << 8) + (lane << 2));
        acc.x = fmaf(v0, bf2f(a0.x), acc.x); acc.y = fmaf(v0, bf2f(a0.y), acc.y);
        acc.z = fmaf(v0, bf2f(a0.z), acc.z); acc.w = fmaf(v0, bf2f(a0.w), acc.w);
    }

    acc.x = fminf(acc.x, MAX_NORM); acc.y = fminf(acc.y, MAX_NORM);
    acc.z = fminf(acc.z, MAX_NORM); acc.w = fminf(acc.w, MAX_NORM);

    // final chain: expmap0+proj -> logmap0 -> relu/clamp -> expmap0+proj (2 reductions)
    bool leader = ((lane & 15) == 0);
    float4 sp = acc;
    if (leader) sp.x = 0.f;
    float n2 = gsum16(sp.x * sp.x + sp.y * sp.y + sp.z * sp.z + sp.w * sp.w);
    float n = fmaxf(sqrtf(n2), MIN_NORM);
    float ep = __expf(n), em = frcp(ep);
    float s1 = 0.5f * (ep - em) * frcp(n);
    float hs2 = s1 * s1 * n2;
    float time = sqrtf(fmaxf(1.f + hs2, EPS));
    float th = fmaxf(time, 1.f + EPS);
    float ac = __logf(th + sqrtf(fmaxf(th * th - 1.f, MIN_NORM)));
    float hn = fmaxf(s1 * n, MIN_NORM);
    float sc = ac * s1 * frcp(hn);
    float4 t;
    t.x = leader ? 0.f : sc * sp.x;
    t.y = sc * sp.y;
    t.z = sc * sp.z;
    t.w = sc * sp.w;
    t.x = fminf(fmaxf(t.x, 0.f), MAX_NORM);
    t.y = fminf(fmaxf(t.y, 0.f), MAX_NORM);
    t.z = fminf(fmaxf(t.z, 0.f), MAX_NORM);
    t.w = fminf(fmaxf(t.w, 0.f), MAX_NORM);
    float t2 = gsum16(t.x * t.x + t.y * t.y + t.z * t.z + t.w * t.w);
    float nt = fmaxf(sqrtf(t2), MIN_NORM);
    float ep3 = __expf(nt), em3 = frcp(ep3);
    float s3 = 0.5f * (ep3 - em3) * frcp(nt);
    float time3 = sqrtf(fmaxf(1.f + s3 * s3 * t2, EPS));
    float4 o;
    o.x = leader ? time3 : s3 * t.x;
    o.y = s3 * t.y;
    o.z = s3 * t.z;
    o.w = s3 * t.w;

    out4[(size_t)r * 64 + lane] = o;
}

extern "C" void kernel_launch(void* const* d_in, const int* in_sizes, int n_in,
                              void* d_out, int out_size, void* d_ws, size_t ws_size,
                              hipStream_t stream) {
    const float* x       = (const float*)d_in[0];
    const float* adj_val = (const float*)d_in[1];
    const float* weight  = (const float*)d_in[2];
    const float* bias    = (const float*)d_in[3];
    const int*   adj_row = (const int*)d_in[4];
    const int*   adj_col = (const int*)d_in[5];

    const int N = NN, E = EE;

    // workspace layout (~19.8 MB, well under the proven 33.3 MB footprint)
    unsigned short* B = (unsigned short*)d_ws;          // N*256 bf16 (xt)
    float* Wt2   = (float*)(B + (size_t)N * 256);       // 65536 f
    int* counts  = (int*)(Wt2 + 65536);                 // N
    int* cursor  = counts + N;                          // N
    int* starts  = cursor + N;                          // N+1
    int* colp    = starts + N + 1;                      // E
    float* valp  = (float*)(colp + E);                  // E

    transpose_kernel<<<256, 256, 0, stream>>>(weight, Wt2);
    fused_front_kernel<<<N / GR, 256, 0, stream>>>(x, Wt2, bias, B);

    zero_kernel<<<(2 * N + 255) / 256, 256, 0, stream>>>(counts, 2 * N);
    hist_kernel<<<(E + 255) / 256, 256, 0, stream>>>(adj_row, counts, E);
    scan_kernel<<<1, 1024, 0, stream>>>(counts, starts, N);
    scatter_kernel<<<(E + 255) / 256, 256, 0, stream>>>(adj_row, adj_col, adj_val,
                                                        starts, cursor, colp, valp, E);

    spmm_final_kernel<<<N / 4, 256, 0, stream>>>(B, colp, valp, starts, (float4*)d_out);
}

// Round 4
// 278.994 us; speedup vs baseline: 2.1684x; 2.1684x over previous
//
#include <hip/hip_runtime.h>
#include <hip/hip_bf16.h>

#define MIN_NORM 1e-15f
#define EPS 1e-7f
#define MAX_NORM 1000.0f

#define NN 30000
#define PP 4
#define DD 64
#define EE 480000

__device__ inline float frcp(float x) { return __builtin_amdgcn_rcpf(x); }
__device__ inline float bf2f(unsigned short u) { return __uint_as_float(((unsigned)u) << 16); }
__device__ inline unsigned short f2bf(float f) {
    unsigned u = __float_as_uint(f);
    return (unsigned short)((u + 0x7fffu + ((u >> 16) & 1u)) >> 16);
}

// ---------- wave-wide helpers (wave = 64 lanes = one point of D=64) ----------
__device__ inline float wsum(float v) {
#pragma unroll
    for (int off = 32; off >= 1; off >>= 1) v += __shfl_xor(v, off, 64);
    return v;
}
__device__ inline void wsum2(float& a, float& b) {
#pragma unroll
    for (int off = 32; off >= 1; off >>= 1) {
        a += __shfl_xor(a, off, 64);
        b += __shfl_xor(b, off, 64);
    }
}

// expmap0 (K=1) + proj: tangent per-lane (lane0 ignored) -> point per-lane.
__device__ inline float expmap0_proj_pt(float v, int lane) {
    float sp = (lane == 0) ? 0.f : v;
    float n2 = wsum(sp * sp);
    float n = fmaxf(sqrtf(n2), MIN_NORM);
    float ep = __expf(n), em = frcp(ep);
    float s = 0.5f * (ep - em) * frcp(n);
    float time = sqrtf(fmaxf(1.f + s * s * n2, EPS));
    return (lane == 0) ? time : s * sp;
}
// logmap0 (K=1): point per-lane -> tangent per-lane (lane0 = 0).
__device__ inline float logmap0_pt(float x, int lane) {
    float sp = (lane == 0) ? 0.f : x;
    float n2 = wsum(sp * sp);
    float n = fmaxf(sqrtf(n2), MIN_NORM);
    float x0 = __shfl(x, 0, 64);
    float th = fmaxf(x0, 1.f + EPS);
    float ac = __logf(th + sqrtf(fmaxf(th * th - 1.f, MIN_NORM)));
    return (lane == 0) ? 0.f : (ac * sp * frcp(n));
}

// ---------- 16-lane-group reduce ----------
__device__ inline float gsum16(float v) {
#pragma unroll
    for (int off = 8; off >= 1; off >>= 1) v += __shfl_xor(v, off, 64);
    return v;
}

// ---------- pack W: Wt2[(k>>2)*1024 + j*4 + (k&3)] = W[j][k]  (float4 idx (k>>2)*256+j) ----------
__global__ void transpose_kernel(const float* __restrict__ w, float* __restrict__ wt2) {
    int j = blockIdx.x;
    int k = threadIdx.x;
    wt2[(k >> 2) * 1024 + j * 4 + (k & 3)] = w[j * 256 + k];
}

// ---------- fused front: logmap0 -> GEMM -> mobius-add(bias) -> logmap0 -> xt(bf16) ----------
#define GR 16
__global__ __launch_bounds__(256) void fused_front_kernel(const float* __restrict__ x,
                                                          const float* __restrict__ wt2,
                                                          const float* __restrict__ bias,
                                                          unsigned short* __restrict__ xt) {
    __shared__ float ulds[GR * 256];
    int tid = threadIdx.x;
    int lane = tid & 63;
    int p = tid >> 6;
    int row0 = blockIdx.x * GR;

    // prologue: batch coalesced loads, then u = logmap0(x) into LDS
    float xv[GR];
#pragma unroll
    for (int i = 0; i < GR; i++) xv[i] = x[(size_t)(row0 + i) * 256 + tid];
#pragma unroll 1
    for (int i = 0; i < GR; i++) {
        float sp = (lane == 0) ? 0.f : xv[i];
        float n2 = wsum(sp * sp);
        float n = fmaxf(sqrtf(n2), MIN_NORM);
        float th = fmaxf(sqrtf(1.f + n2), 1.f + EPS);
        float ac = __logf(th + sqrtf(fmaxf(th * th - 1.f, MIN_NORM)));
        ulds[i * 256 + tid] = (lane == 0) ? 0.f : ac * sp * frcp(n);
    }

    // hoisted bias tangent (wave p == point p): usp (lane0=0), U2 = ||usp||^2
    float b = bias[p * 64 + lane];
    float y = expmap0_proj_pt(b, lane);
    float usp = logmap0_pt(y, lane);
    float U2 = wsum(usp * usp);

    __syncthreads();

    // GEMM: 2 rows x 8 cols/thread. rt=tid>>5 -> rows {2rt,2rt+1}; ct=tid&31 -> cols {j*32+ct}
    int rt = tid >> 5;
    int ct = tid & 31;
    const float4* U4 = (const float4*)ulds;   // [GR][64]
    const float4* w4 = (const float4*)wt2;    // [64][256]  (idx kc*256 + col)
    float acc0[8], acc1[8];
#pragma unroll
    for (int j = 0; j < 8; j++) { acc0[j] = 0.f; acc1[j] = 0.f; }
#pragma unroll 2
    for (int kc = 0; kc < 64; kc++) {
        float4 u0 = U4[(2 * rt) * 64 + kc];       // half-wave broadcast
        float4 u1 = U4[(2 * rt + 1) * 64 + kc];
#pragma unroll
        for (int j = 0; j < 8; j++) {
            float4 wv = w4[kc * 256 + j * 32 + ct];  // coalesced
            acc0[j] = fmaf(u0.x, wv.x, acc0[j]);
            acc0[j] = fmaf(u0.y, wv.y, acc0[j]);
            acc0[j] = fmaf(u0.z, wv.z, acc0[j]);
            acc0[j] = fmaf(u0.w, wv.w, acc0[j]);
            acc1[j] = fmaf(u1.x, wv.x, acc1[j]);
            acc1[j] = fmaf(u1.y, wv.y, acc1[j]);
            acc1[j] = fmaf(u1.z, wv.z, acc1[j]);
            acc1[j] = fmaf(u1.w, wv.w, acc1[j]);
        }
    }
    __syncthreads();
    // conflict-free write-back: consecutive addresses per half-wave (2-way max = free)
#pragma unroll
    for (int j = 0; j < 8; j++) {
        ulds[(2 * rt) * 256 + j * 32 + ct] = acc0[j];
        ulds[(2 * rt + 1) * 256 + j * 32 + ct] = acc1[j];
    }
    __syncthreads();

    // epilogue: per row, 2 reductions + scalar algebra
#pragma unroll 1
    for (int i = 0; i < GR; i++) {
        float mu = ulds[i * 256 + tid];
        float musp = (lane == 0) ? 0.f : mu;
        float n2 = musp * musp;
        float duu = musp * usp;
        wsum2(n2, duu);

        float n = fmaxf(sqrtf(n2), MIN_NORM);
        float ep = __expf(n), em = frcp(ep);
        float s = 0.5f * (ep - em) * frcp(n);     // sinh(n)/n
        float hs2 = s * s * n2;                    // ||h_sp||^2
        float h0 = sqrtf(fmaxf(1.f + hs2, EPS));   // h time
        float hs = s * musp;                       // h space (lane0=0)

        float yn = fmaxf(s * n, MIN_NORM);         // ||h_sp||
        float dhu = s * duu;                       // <h_sp, usp>
        float alpha = dhu * frcp(yn);
        float g = alpha * (1.f - h0);
        float ux = dhu - g * yn;                   // <h_sp, w_sp>
        float t = ux * frcp(fmaxf(h0, MIN_NORM));
        float w2 = U2 - 2.f * g * alpha + g * g;   // ||w_sp||^2
        float md = w2 - t * t;                     // minkowski dot
        float normu = fminf(sqrtf(fmaxf(md, EPS)), MAX_NORM);
        float theta = fmaxf(normu, MIN_NORM);
        float ep2 = __expf(theta), em2 = frcp(ep2);
        float ch = 0.5f * (ep2 + em2);
        float shot = 0.5f * (ep2 - em2) * frcp(theta);

        float wsp = (lane == 0) ? 0.f : (usp - g * (hs * frcp(yn)));
        float rsp = ch * hs + shot * wsp;          // result space (lane0=0)
        float rn2 = ch * ch * hs2 + 2.f * ch * shot * ux + shot * shot * w2;
        float rtime = sqrtf(fmaxf(1.f + rn2, EPS));

        float th2 = fmaxf(rtime, 1.f + EPS);
        float ac2 = __logf(th2 + sqrtf(fmaxf(th2 * th2 - 1.f, MIN_NORM)));
        float rn = fmaxf(sqrtf(rn2), MIN_NORM);
        float o = ac2 * rsp * frcp(rn);

        xt[(size_t)(row0 + i) * 256 + tid] = f2bf(o);
    }
}

// ---------- CSR build ----------
__global__ void zero_kernel(int* __restrict__ p, int n) {
    int i = blockIdx.x * 256 + threadIdx.x;
    if (i < n) p[i] = 0;
}
__global__ void hist_kernel(const int* __restrict__ row, int* __restrict__ counts, int E) {
    int e = blockIdx.x * 256 + threadIdx.x;
    if (e < E) atomicAdd(&counts[row[e]], 1);
}

#define SCH 30
__global__ __launch_bounds__(1024) void scan_kernel(const int* __restrict__ counts,
                                                    int* __restrict__ starts, int n) {
    int tid = threadIdx.x, lane = tid & 63, wv = tid >> 6;
    int i0 = tid * SCH;
    int c[SCH];
    int s = 0;
#pragma unroll
    for (int j = 0; j < SCH; j++) {
        int idx = i0 + j;
        int v = (idx < n) ? counts[idx] : 0;
        c[j] = v;
        s += v;
    }
    int incl = s;
#pragma unroll
    for (int off = 1; off < 64; off <<= 1) {
        int t = __shfl_up(incl, off, 64);
        if (lane >= off) incl += t;
    }
    __shared__ int wtot[16];
    if (lane == 63) wtot[wv] = incl;
    __syncthreads();
    if (wv == 0 && lane < 16) {
        int v = wtot[lane];
        int sc = v;
#pragma unroll
        for (int off = 1; off < 16; off <<= 1) {
            int t = __shfl_up(sc, off, 64);
            if (lane >= off) sc += t;
        }
        wtot[lane] = sc - v;  // exclusive
    }
    __syncthreads();
    int run = incl - s + wtot[wv];
#pragma unroll
    for (int j = 0; j < SCH; j++) {
        int idx = i0 + j;
        if (idx < n) starts[idx] = run;
        run += c[j];
    }
    if (tid == 1023) starts[n] = run;
}

__global__ void scatter_kernel(const int* __restrict__ row, const int* __restrict__ col,
                               const float* __restrict__ val, const int* __restrict__ starts,
                               int* __restrict__ cursor, int* __restrict__ colp,
                               float* __restrict__ valp, int E) {
    int e = blockIdx.x * 256 + threadIdx.x;
    if (e < E) {
        int r = row[e];
        int pos = starts[r] + atomicAdd(&cursor[r], 1);
        colp[pos] = col[e];
        valp[pos] = val[e];
    }
}

// ---------- SpMM (wave/row, bf16 gather) + fused final chain ----------
__global__ __launch_bounds__(256) void spmm_final_kernel(const unsigned short* __restrict__ xt,
                                                         const int* __restrict__ colp,
                                                         const float* __restrict__ valp,
                                                         const int* __restrict__ starts,
                                                         float4* __restrict__ out4) {
    int w = threadIdx.x >> 6;
    int lane = threadIdx.x & 63;
    int r = blockIdx.x * 4 + w;
    int s = starts[r], e = starts[r + 1];

    float4 acc = {0.f, 0.f, 0.f, 0.f};
    int i = s;
    for (; i + 4 <= e; i += 4) {
        int c0 = colp[i], c1 = colp[i + 1], c2 = colp[i + 2], c3 = colp[i + 3];
        float v0 = valp[i], v1 = valp[i + 1], v2 = valp[i + 2], v3 = valp[i + 3];
        ushort4 a0 = *(const ushort4*)(xt + ((size_t)c0 << 8) + (lane << 2));
        ushort4 a1 = *(const ushort4*)(xt + ((size_t)c1 << 8) + (lane << 2));
        ushort4 a2 = *(const ushort4*)(xt + ((size_t)c2 << 8) + (lane << 2));
        ushort4 a3 = *(const ushort4*)(xt + ((size_t)c3 << 8) + (lane << 2));
        acc.x = fmaf(v0, bf2f(a0.x), acc.x); acc.y = fmaf(v0, bf2f(a0.y), acc.y);
        acc.z = fmaf(v0, bf2f(a0.z), acc.z); acc.w = fmaf(v0, bf2f(a0.w), acc.w);
        acc.x = fmaf(v1, bf2f(a1.x), acc.x); acc.y = fmaf(v1, bf2f(a1.y), acc.y);
        acc.z = fmaf(v1, bf2f(a1.z), acc.z); acc.w = fmaf(v1, bf2f(a1.w), acc.w);
        acc.x = fmaf(v2, bf2f(a2.x), acc.x); acc.y = fmaf(v2, bf2f(a2.y), acc.y);
        acc.z = fmaf(v2, bf2f(a2.z), acc.z); acc.w = fmaf(v2, bf2f(a2.w), acc.w);
        acc.x = fmaf(v3, bf2f(a3.x), acc.x); acc.y = fmaf(v3, bf2f(a3.y), acc.y);
        acc.z = fmaf(v3, bf2f(a3.z), acc.z); acc.w = fmaf(v3, bf2f(a3.w), acc.w);
    }
    for (; i < e; i++) {
        int c0 = colp[i];
        float v0 = valp[i];
        ushort4 a0 = *(const ushort4*)(xt + ((size_t)c0 << 8) + (lane << 2));
        acc.x = fmaf(v0, bf2f(a0.x), acc.x); acc.y = fmaf(v0, bf2f(a0.y), acc.y);
        acc.z = fmaf(v0, bf2f(a0.z), acc.z); acc.w = fmaf(v0, bf2f(a0.w), acc.w);
    }

    acc.x = fminf(acc.x, MAX_NORM); acc.y = fminf(acc.y, MAX_NORM);
    acc.z = fminf(acc.z, MAX_NORM); acc.w = fminf(acc.w, MAX_NORM);

    // final chain: expmap0+proj -> logmap0 -> relu/clamp -> expmap0+proj (2 reductions)
    bool leader = ((lane & 15) == 0);
    float4 sp = acc;
    if (leader) sp.x = 0.f;
    float n2 = gsum16(sp.x * sp.x + sp.y * sp.y + sp.z * sp.z + sp.w * sp.w);
    float n = fmaxf(sqrtf(n2), MIN_NORM);
    float ep = __expf(n), em = frcp(ep);
    float s1 = 0.5f * (ep - em) * frcp(n);
    float hs2 = s1 * s1 * n2;
    float time = sqrtf(fmaxf(1.f + hs2, EPS));
    float th = fmaxf(time, 1.f + EPS);
    float ac = __logf(th + sqrtf(fmaxf(th * th - 1.f, MIN_NORM)));
    float hn = fmaxf(s1 * n, MIN_NORM);
    float sc = ac * s1 * frcp(hn);
    float4 t;
    t.x = leader ? 0.f : sc * sp.x;
    t.y = sc * sp.y;
    t.z = sc * sp.z;
    t.w = sc * sp.w;
    t.x = fminf(fmaxf(t.x, 0.f), MAX_NORM);
    t.y = fminf(fmaxf(t.y, 0.f), MAX_NORM);
    t.z = fminf(fmaxf(t.z, 0.f), MAX_NORM);
    t.w = fminf(fmaxf(t.w, 0.f), MAX_NORM);
    float t2 = gsum16(t.x * t.x + t.y * t.y + t.z * t.z + t.w * t.w);
    float nt = fmaxf(sqrtf(t2), MIN_NORM);
    float ep3 = __expf(nt), em3 = frcp(ep3);
    float s3 = 0.5f * (ep3 - em3) * frcp(nt);
    float time3 = sqrtf(fmaxf(1.f + s3 * s3 * t2, EPS));
    float4 o;
    o.x = leader ? time3 : s3 * t.x;
    o.y = s3 * t.y;
    o.z = s3 * t.z;
    o.w = s3 * t.w;

    out4[(size_t)r * 64 + lane] = o;
}

extern "C" void kernel_launch(void* const* d_in, const int* in_sizes, int n_in,
                              void* d_out, int out_size, void* d_ws, size_t ws_size,
                              hipStream_t stream) {
    const float* x       = (const float*)d_in[0];
    const float* adj_val = (const float*)d_in[1];
    const float* weight  = (const float*)d_in[2];
    const float* bias    = (const float*)d_in[3];
    const int*   adj_row = (const int*)d_in[4];
    const int*   adj_col = (const int*)d_in[5];

    const int N = NN, E = EE;

    unsigned short* B = (unsigned short*)d_ws;          // N*256 bf16 (xt)
    float* Wt2   = (float*)(B + (size_t)N * 256);       // 65536 f
    int* counts  = (int*)(Wt2 + 65536);                 // N
    int* cursor  = counts + N;                          // N
    int* starts  = cursor + N;                          // N+1
    int* colp    = starts + N + 1;                      // E
    float* valp  = (float*)(colp + E);                  // E

    transpose_kernel<<<256, 256, 0, stream>>>(weight, Wt2);
    fused_front_kernel<<<N / GR, 256, 0, stream>>>(x, Wt2, bias, B);

    zero_kernel<<<(2 * N + 255) / 256, 256, 0, stream>>>(counts, 2 * N);
    hist_kernel<<<(E + 255) / 256, 256, 0, stream>>>(adj_row, counts, E);
    scan_kernel<<<1, 1024, 0, stream>>>(counts, starts, N);
    scatter_kernel<<<(E + 255) / 256, 256, 0, stream>>>(adj_row, adj_col, adj_val,
                                                        starts, cursor, colp, valp, E);

    spmm_final_kernel<<<N / 4, 256, 0, stream>>>(B, colp, valp, starts, (float4*)d_out);
}

// Round 5
// 190.827 us; speedup vs baseline: 3.1702x; 1.4620x over previous
//
#include <hip/hip_runtime.h>
#include <hip/hip_bf16.h>

#define MIN_NORM 1e-15f
#define EPS 1e-7f
#define MAX_NORM 1000.0f

#define NN 30000
#define PP 4
#define DD 64
#define EE 480000

typedef __attribute__((ext_vector_type(8))) short short8v;
typedef __attribute__((ext_vector_type(4))) float float4v;

__device__ inline float frcp(float x) { return __builtin_amdgcn_rcpf(x); }
__device__ inline float bf2f(unsigned short u) { return __uint_as_float(((unsigned)u) << 16); }
__device__ inline unsigned short f2bf(float f) {
    unsigned u = __float_as_uint(f);
    return (unsigned short)((u + 0x7fffu + ((u >> 16) & 1u)) >> 16);
}

// ---------- wave-wide helpers ----------
__device__ inline float wsum(float v) {
#pragma unroll
    for (int off = 32; off >= 1; off >>= 1) v += __shfl_xor(v, off, 64);
    return v;
}
__device__ inline void wsum2(float& a, float& b) {
#pragma unroll
    for (int off = 32; off >= 1; off >>= 1) {
        a += __shfl_xor(a, off, 64);
        b += __shfl_xor(b, off, 64);
    }
}
__device__ inline float expmap0_proj_pt(float v, int lane) {
    float sp = (lane == 0) ? 0.f : v;
    float n2 = wsum(sp * sp);
    float n = fmaxf(sqrtf(n2), MIN_NORM);
    float ep = __expf(n), em = frcp(ep);
    float s = 0.5f * (ep - em) * frcp(n);
    float time = sqrtf(fmaxf(1.f + s * s * n2, EPS));
    return (lane == 0) ? time : s * sp;
}
__device__ inline float logmap0_pt(float x, int lane) {
    float sp = (lane == 0) ? 0.f : x;
    float n2 = wsum(sp * sp);
    float n = fmaxf(sqrtf(n2), MIN_NORM);
    float x0 = __shfl(x, 0, 64);
    float th = fmaxf(x0, 1.f + EPS);
    float ac = __logf(th + sqrtf(fmaxf(th * th - 1.f, MIN_NORM)));
    return (lane == 0) ? 0.f : (ac * sp * frcp(n));
}
__device__ inline float gsum16(float v) {
#pragma unroll
    for (int off = 8; off >= 1; off >>= 1) v += __shfl_xor(v, off, 64);
    return v;
}

// ---------- pack W into MFMA B-fragment order, split bf16 hi/lo ----------
// chunk tt in [0,8192): lane=tt&63, ks=(tt>>6)&7, nt=tt>>9
// element e in [0,8): col = nt*16+(lane&15), k = ks*32+(lane>>4)*8+e ; B[k][col]=W[col][k]
__global__ void pack_w_kernel(const float* __restrict__ w,
                              unsigned short* __restrict__ bhi,
                              unsigned short* __restrict__ blo) {
    int tt = blockIdx.x * 256 + threadIdx.x;  // [0, 8192)
    int lane = tt & 63;
    int ks = (tt >> 6) & 7;
    int nt = tt >> 9;
    int col = nt * 16 + (lane & 15);
    int kb = ks * 32 + (lane >> 4) * 8;
#pragma unroll
    for (int e = 0; e < 8; e++) {
        float v = w[col * 256 + kb + e];
        unsigned short h = f2bf(v);
        bhi[tt * 8 + e] = h;
        blo[tt * 8 + e] = f2bf(v - bf2f(h));
    }
}

// ---------- fused front: logmap0 -> emulated-f32 MFMA GEMM -> mobius -> logmap0 -> xt(bf16) ----------
#define GR 16
#define UPITCH 264            // bf16 elems per row (528 B)
#define MUPITCH 260           // f32 elems per row
__global__ __launch_bounds__(256) void fused_front_kernel(const float* __restrict__ x,
                                                          const unsigned short* __restrict__ bhi,
                                                          const unsigned short* __restrict__ blo,
                                                          const float* __restrict__ bias,
                                                          unsigned short* __restrict__ xt) {
    __shared__ __align__(16) char smem[17408];
    unsigned short* uh = (unsigned short*)smem;            // [GR][UPITCH]
    unsigned short* ul = (unsigned short*)(smem + 8448);   // [GR][UPITCH]
    float* mulds = (float*)smem;                           // [GR][MUPITCH] (reused)

    int tid = threadIdx.x;
    int lane = tid & 63;
    int wv = tid >> 6;
    int row0 = blockIdx.x * GR;

    // prologue: u = logmap0(x), split to bf16 hi/lo in LDS
    float xv[GR];
#pragma unroll
    for (int i = 0; i < GR; i++) xv[i] = x[(size_t)(row0 + i) * 256 + tid];
#pragma unroll 1
    for (int i = 0; i < GR; i++) {
        float sp = (lane == 0) ? 0.f : xv[i];
        float n2 = wsum(sp * sp);
        float n = fmaxf(sqrtf(n2), MIN_NORM);
        float th = fmaxf(sqrtf(1.f + n2), 1.f + EPS);
        float ac = __logf(th + sqrtf(fmaxf(th * th - 1.f, MIN_NORM)));
        float u = (lane == 0) ? 0.f : ac * sp * frcp(n);
        unsigned short h = f2bf(u);
        uh[i * UPITCH + tid] = h;
        ul[i * UPITCH + tid] = f2bf(u - bf2f(h));
    }

    // hoisted bias tangent (wave wv == point wv)
    float b = bias[wv * 64 + lane];
    float y = expmap0_proj_pt(b, lane);
    float usp = logmap0_pt(y, lane);
    float U2 = wsum(usp * usp);

    __syncthreads();

    // MFMA GEMM: M=16 rows, N=256 (wave wv owns cols [wv*64, wv*64+64) as 4 n-tiles), K=256
    float4v acc[4];
#pragma unroll
    for (int j = 0; j < 4; j++) acc[j] = (float4v){0.f, 0.f, 0.f, 0.f};
    // A frag byte offset: row=(lane&15), k=(lane>>4)*8 + ks*32
    int abyte = (lane & 15) * (UPITCH * 2) + (lane >> 4) * 16;
#pragma unroll
    for (int ks = 0; ks < 8; ks++) {
        short8v Ah = *(const short8v*)(smem + abyte + ks * 64);
        short8v Al = *(const short8v*)(smem + 8448 + abyte + ks * 64);
#pragma unroll
        for (int j = 0; j < 4; j++) {
            size_t chunk = ((size_t)((wv * 4 + j) * 8 + ks) * 64 + lane) * 8;
            short8v Bh = *(const short8v*)(bhi + chunk);
            short8v Bl = *(const short8v*)(blo + chunk);
            acc[j] = __builtin_amdgcn_mfma_f32_16x16x32_bf16(Ah, Bh, acc[j], 0, 0, 0);
            acc[j] = __builtin_amdgcn_mfma_f32_16x16x32_bf16(Al, Bh, acc[j], 0, 0, 0);
            acc[j] = __builtin_amdgcn_mfma_f32_16x16x32_bf16(Ah, Bl, acc[j], 0, 0, 0);
        }
    }
    __syncthreads();  // all A-reads done before overwriting LDS with mu

    // D write: col = (wv*4+j)*16 + (lane&15), row = (lane>>4)*4 + reg
#pragma unroll
    for (int j = 0; j < 4; j++) {
        int col = (wv * 4 + j) * 16 + (lane & 15);
        int rbase = (lane >> 4) * 4;
#pragma unroll
        for (int reg = 0; reg < 4; reg++) {
            mulds[(rbase + reg) * MUPITCH + col] = acc[j][reg];
        }
    }
    __syncthreads();

    // epilogue: per row, 2 reductions + scalar algebra
#pragma unroll 1
    for (int i = 0; i < GR; i++) {
        float mu = mulds[i * MUPITCH + tid];
        float musp = (lane == 0) ? 0.f : mu;
        float n2 = musp * musp;
        float duu = musp * usp;
        wsum2(n2, duu);

        float n = fmaxf(sqrtf(n2), MIN_NORM);
        float ep = __expf(n), em = frcp(ep);
        float s = 0.5f * (ep - em) * frcp(n);
        float hs2 = s * s * n2;
        float h0 = sqrtf(fmaxf(1.f + hs2, EPS));
        float hs = s * musp;

        float yn = fmaxf(s * n, MIN_NORM);
        float dhu = s * duu;
        float alpha = dhu * frcp(yn);
        float g = alpha * (1.f - h0);
        float ux = dhu - g * yn;
        float t = ux * frcp(fmaxf(h0, MIN_NORM));
        float w2 = U2 - 2.f * g * alpha + g * g;
        float md = w2 - t * t;
        float normu = fminf(sqrtf(fmaxf(md, EPS)), MAX_NORM);
        float theta = fmaxf(normu, MIN_NORM);
        float ep2 = __expf(theta), em2 = frcp(ep2);
        float ch = 0.5f * (ep2 + em2);
        float shot = 0.5f * (ep2 - em2) * frcp(theta);

        float wsp = (lane == 0) ? 0.f : (usp - g * (hs * frcp(yn)));
        float rsp = ch * hs + shot * wsp;
        float rn2 = ch * ch * hs2 + 2.f * ch * shot * ux + shot * shot * w2;
        float rtime = sqrtf(fmaxf(1.f + rn2, EPS));

        float th2 = fmaxf(rtime, 1.f + EPS);
        float ac2 = __logf(th2 + sqrtf(fmaxf(th2 * th2 - 1.f, MIN_NORM)));
        float rn = fmaxf(sqrtf(rn2), MIN_NORM);
        float o = ac2 * rsp * frcp(rn);

        xt[(size_t)(row0 + i) * 256 + tid] = f2bf(o);
    }
}

// ---------- CSR build ----------
__global__ void zero_kernel(int* __restrict__ p, int n) {
    int i = blockIdx.x * 256 + threadIdx.x;
    if (i < n) p[i] = 0;
}
__global__ void hist_kernel(const int* __restrict__ row, int* __restrict__ counts, int E) {
    int e = blockIdx.x * 256 + threadIdx.x;
    if (e < E) atomicAdd(&counts[row[e]], 1);
}

#define SCH 30
__global__ __launch_bounds__(1024) void scan_kernel(const int* __restrict__ counts,
                                                    int* __restrict__ starts, int n) {
    int tid = threadIdx.x, lane = tid & 63, wv = tid >> 6;
    int i0 = tid * SCH;
    int c[SCH];
    int s = 0;
#pragma unroll
    for (int j = 0; j < SCH; j++) {
        int idx = i0 + j;
        int v = (idx < n) ? counts[idx] : 0;
        c[j] = v;
        s += v;
    }
    int incl = s;
#pragma unroll
    for (int off = 1; off < 64; off <<= 1) {
        int t = __shfl_up(incl, off, 64);
        if (lane >= off) incl += t;
    }
    __shared__ int wtot[16];
    if (lane == 63) wtot[wv] = incl;
    __syncthreads();
    if (wv == 0 && lane < 16) {
        int v = wtot[lane];
        int sc = v;
#pragma unroll
        for (int off = 1; off < 16; off <<= 1) {
            int t = __shfl_up(sc, off, 64);
            if (lane >= off) sc += t;
        }
        wtot[lane] = sc - v;  // exclusive
    }
    __syncthreads();
    int run = incl - s + wtot[wv];
#pragma unroll
    for (int j = 0; j < SCH; j++) {
        int idx = i0 + j;
        if (idx < n) starts[idx] = run;
        run += c[j];
    }
    if (tid == 1023) starts[n] = run;
}

__global__ void scatter_kernel(const int* __restrict__ row, const int* __restrict__ col,
                               const float* __restrict__ val, const int* __restrict__ starts,
                               int* __restrict__ cursor, int* __restrict__ colp,
                               float* __restrict__ valp, int E) {
    int e = blockIdx.x * 256 + threadIdx.x;
    if (e < E) {
        int r = row[e];
        int pos = starts[r] + atomicAdd(&cursor[r], 1);
        colp[pos] = col[e];
        valp[pos] = val[e];
    }
}

// ---------- SpMM (wave/row, bf16 gather) + fused final chain ----------
__global__ __launch_bounds__(256) void spmm_final_kernel(const unsigned short* __restrict__ xt,
                                                         const int* __restrict__ colp,
                                                         const float* __restrict__ valp,
                                                         const int* __restrict__ starts,
                                                         float4* __restrict__ out4) {
    int w = threadIdx.x >> 6;
    int lane = threadIdx.x & 63;
    int r = blockIdx.x * 4 + w;
    int s = starts[r], e = starts[r + 1];

    float4 acc = {0.f, 0.f, 0.f, 0.f};
    int i = s;
    for (; i + 4 <= e; i += 4) {
        int c0 = colp[i], c1 = colp[i + 1], c2 = colp[i + 2], c3 = colp[i + 3];
        float v0 = valp[i], v1 = valp[i + 1], v2 = valp[i + 2], v3 = valp[i + 3];
        ushort4 a0 = *(const ushort4*)(xt + ((size_t)c0 << 8) + (lane << 2));
        ushort4 a1 = *(const ushort4*)(xt + ((size_t)c1 << 8) + (lane << 2));
        ushort4 a2 = *(const ushort4*)(xt + ((size_t)c2 << 8) + (lane << 2));
        ushort4 a3 = *(const ushort4*)(xt + ((size_t)c3 << 8) + (lane << 2));
        acc.x = fmaf(v0, bf2f(a0.x), acc.x); acc.y = fmaf(v0, bf2f(a0.y), acc.y);
        acc.z = fmaf(v0, bf2f(a0.z), acc.z); acc.w = fmaf(v0, bf2f(a0.w), acc.w);
        acc.x = fmaf(v1, bf2f(a1.x), acc.x); acc.y = fmaf(v1, bf2f(a1.y), acc.y);
        acc.z = fmaf(v1, bf2f(a1.z), acc.z); acc.w = fmaf(v1, bf2f(a1.w), acc.w);
        acc.x = fmaf(v2, bf2f(a2.x), acc.x); acc.y = fmaf(v2, bf2f(a2.y), acc.y);
        acc.z = fmaf(v2, bf2f(a2.z), acc.z); acc.w = fmaf(v2, bf2f(a2.w), acc.w);
        acc.x = fmaf(v3, bf2f(a3.x), acc.x); acc.y = fmaf(v3, bf2f(a3.y), acc.y);
        acc.z = fmaf(v3, bf2f(a3.z), acc.z); acc.w = fmaf(v3, bf2f(a3.w), acc.w);
    }
    for (; i < e; i++) {
        int c0 = colp[i];
        float v0 = valp[i];
        ushort4 a0 = *(const ushort4*)(xt + ((size_t)c0 << 8) + (lane << 2));
        acc.x = fmaf(v0, bf2f(a0.x), acc.x); acc.y = fmaf(v0, bf2f(a0.y), acc.y);
        acc.z = fmaf(v0, bf2f(a0.z), acc.z); acc.w = fmaf(v0, bf2f(a0.w), acc.w);
    }

    acc.x = fminf(acc.x, MAX_NORM); acc.y = fminf(acc.y, MAX_NORM);
    acc.z = fminf(acc.z, MAX_NORM); acc.w = fminf(acc.w, MAX_NORM);

    bool leader = ((lane & 15) == 0);
    float4 sp = acc;
    if (leader) sp.x = 0.f;
    float n2 = gsum16(sp.x * sp.x + sp.y * sp.y + sp.z * sp.z + sp.w * sp.w);
    float n = fmaxf(sqrtf(n2), MIN_NORM);
    float ep = __expf(n), em = frcp(ep);
    float s1 = 0.5f * (ep - em) * frcp(n);
    float hs2 = s1 * s1 * n2;
    float time = sqrtf(fmaxf(1.f + hs2, EPS));
    float th = fmaxf(time, 1.f + EPS);
    float ac = __logf(th + sqrtf(fmaxf(th * th - 1.f, MIN_NORM)));
    float hn = fmaxf(s1 * n, MIN_NORM);
    float sc = ac * s1 * frcp(hn);
    float4 t;
    t.x = leader ? 0.f : sc * sp.x;
    t.y = sc * sp.y;
    t.z = sc * sp.z;
    t.w = sc * sp.w;
    t.x = fminf(fmaxf(t.x, 0.f), MAX_NORM);
    t.y = fminf(fmaxf(t.y, 0.f), MAX_NORM);
    t.z = fminf(fmaxf(t.z, 0.f), MAX_NORM);
    t.w = fminf(fmaxf(t.w, 0.f), MAX_NORM);
    float t2 = gsum16(t.x * t.x + t.y * t.y + t.z * t.z + t.w * t.w);
    float nt = fmaxf(sqrtf(t2), MIN_NORM);
    float ep3 = __expf(nt), em3 = frcp(ep3);
    float s3 = 0.5f * (ep3 - em3) * frcp(nt);
    float time3 = sqrtf(fmaxf(1.f + s3 * s3 * t2, EPS));
    float4 o;
    o.x = leader ? time3 : s3 * t.x;
    o.y = s3 * t.y;
    o.z = s3 * t.z;
    o.w = s3 * t.w;

    out4[(size_t)r * 64 + lane] = o;
}

extern "C" void kernel_launch(void* const* d_in, const int* in_sizes, int n_in,
                              void* d_out, int out_size, void* d_ws, size_t ws_size,
                              hipStream_t stream) {
    const float* x       = (const float*)d_in[0];
    const float* adj_val = (const float*)d_in[1];
    const float* weight  = (const float*)d_in[2];
    const float* bias    = (const float*)d_in[3];
    const int*   adj_row = (const int*)d_in[4];
    const int*   adj_col = (const int*)d_in[5];

    const int N = NN, E = EE;

    unsigned short* B   = (unsigned short*)d_ws;          // N*256 bf16 (xt)
    unsigned short* Whi = B + (size_t)N * 256;            // 65536 ushort
    unsigned short* Wlo = Whi + 65536;                    // 65536 ushort
    int* counts  = (int*)(Wlo + 65536);                   // N
    int* cursor  = counts + N;                            // N
    int* starts  = cursor + N;                            // N+1
    int* colp    = starts + N + 1;                        // E
    float* valp  = (float*)(colp + E);                    // E

    pack_w_kernel<<<32, 256, 0, stream>>>(weight, Whi, Wlo);
    fused_front_kernel<<<N / GR, 256, 0, stream>>>(x, Whi, Wlo, bias, B);

    zero_kernel<<<(2 * N + 255) / 256, 256, 0, stream>>>(counts, 2 * N);
    hist_kernel<<<(E + 255) / 256, 256, 0, stream>>>(adj_row, counts, E);
    scan_kernel<<<1, 1024, 0, stream>>>(counts, starts, N);
    scatter_kernel<<<(E + 255) / 256, 256, 0, stream>>>(adj_row, adj_col, adj_val,
                                                        starts, cursor, colp, valp, E);

    spmm_final_kernel<<<N / 4, 256, 0, stream>>>(B, colp, valp, starts, (float4*)d_out);
}

// Round 6
// 166.851 us; speedup vs baseline: 3.6258x; 1.1437x over previous
//
#include <hip/hip_runtime.h>
#include <hip/hip_bf16.h>

#define MIN_NORM 1e-15f
#define EPS 1e-7f
#define MAX_NORM 1000.0f

#define NN 30000
#define PP 4
#define DD 64
#define EE 480000

typedef __attribute__((ext_vector_type(8))) short short8v;
typedef __attribute__((ext_vector_type(4))) float float4v;

__device__ inline float frcp(float x) { return __builtin_amdgcn_rcpf(x); }
__device__ inline float bf2f(unsigned short u) { return __uint_as_float(((unsigned)u) << 16); }
__device__ inline unsigned short f2bf(float f) {
    unsigned u = __float_as_uint(f);
    return (unsigned short)((u + 0x7fffu + ((u >> 16) & 1u)) >> 16);
}

// ---------- wave-wide helpers (bias stage only) ----------
__device__ inline float wsum(float v) {
#pragma unroll
    for (int off = 32; off >= 1; off >>= 1) v += __shfl_xor(v, off, 64);
    return v;
}
__device__ inline float expmap0_proj_pt(float v, int lane) {
    float sp = (lane == 0) ? 0.f : v;
    float n2 = wsum(sp * sp);
    float n = fmaxf(sqrtf(n2), MIN_NORM);
    float ep = __expf(n), em = frcp(ep);
    float s = 0.5f * (ep - em) * frcp(n);
    float time = sqrtf(fmaxf(1.f + s * s * n2, EPS));
    return (lane == 0) ? time : s * sp;
}
__device__ inline float logmap0_pt(float x, int lane) {
    float sp = (lane == 0) ? 0.f : x;
    float n2 = wsum(sp * sp);
    float n = fmaxf(sqrtf(n2), MIN_NORM);
    float x0 = __shfl(x, 0, 64);
    float th = fmaxf(x0, 1.f + EPS);
    float ac = __logf(th + sqrtf(fmaxf(th * th - 1.f, MIN_NORM)));
    return (lane == 0) ? 0.f : (ac * sp * frcp(n));
}

// ---------- 16-lane-group batched reduces ----------
__device__ inline float gsum16(float v) {
#pragma unroll
    for (int off = 8; off >= 1; off >>= 1) v += __shfl_xor(v, off, 64);
    return v;
}
__device__ inline void gsum16x4(float& a, float& b, float& c, float& d) {
#pragma unroll
    for (int off = 8; off >= 1; off >>= 1) {
        a += __shfl_xor(a, off, 64);
        b += __shfl_xor(b, off, 64);
        c += __shfl_xor(c, off, 64);
        d += __shfl_xor(d, off, 64);
    }
}

// ---------- pack W into MFMA B-fragment order, split bf16 hi/lo ----------
__global__ void pack_w_kernel(const float* __restrict__ w,
                              unsigned short* __restrict__ bhi,
                              unsigned short* __restrict__ blo) {
    int tt = blockIdx.x * 256 + threadIdx.x;  // [0, 8192)
    int lane = tt & 63;
    int ks = (tt >> 6) & 7;
    int nt = tt >> 9;
    int col = nt * 16 + (lane & 15);
    int kb = ks * 32 + (lane >> 4) * 8;
#pragma unroll
    for (int e = 0; e < 8; e++) {
        float v = w[col * 256 + kb + e];
        unsigned short h = f2bf(v);
        bhi[tt * 8 + e] = h;
        blo[tt * 8 + e] = f2bf(v - bf2f(h));
    }
}

// ---------- fused front ----------
#define GR 16
#define UPITCH 264            // bf16 elems per row (528 B)
#define DPITCH 17             // mu col-major pitch (16 rows + 1 pad)
__global__ __launch_bounds__(256) void fused_front_kernel(const float* __restrict__ x,
                                                          const unsigned short* __restrict__ bhi,
                                                          const unsigned short* __restrict__ blo,
                                                          const float* __restrict__ bias,
                                                          unsigned short* __restrict__ xt) {
    __shared__ __align__(16) char smem[18464];
    unsigned short* uh = (unsigned short*)smem;            // [16][264] bf16 hi
    unsigned short* ul = (unsigned short*)(smem + 8448);   // [16][264] bf16 lo
    float* mulds = (float*)smem;                           // col-major [256][17] (aliased)
    float* uspL  = (float*)(smem + 17408);                 // [256] bias tangent
    float* u2L   = (float*)(smem + 18432);                 // [4] ||usp||^2 per point

    int tid = threadIdx.x;
    int lane = tid & 63;
    int wv = tid >> 6;
    int row0 = blockIdx.x * GR;

    // ---- bias tangent (wave wv == point wv), staged to LDS ----
    {
        float b = bias[wv * 64 + lane];
        float y = expmap0_proj_pt(b, lane);
        float usp = logmap0_pt(y, lane);
        float U2 = wsum(usp * usp);
        uspL[wv * 64 + lane] = usp;
        if (lane == 0) u2L[wv] = U2;
    }

    // ---- prologue (transposed): thread (r = tid>>4, l = tid&15) ----
    int r = tid >> 4, l = tid & 15;
    {
        const float4* xr = (const float4*)(x + (size_t)(row0 + r) * 256);
        float4 a[4];
#pragma unroll
        for (int p = 0; p < 4; p++) a[p] = xr[p * 16 + l];
        float s0, s1, s2, s3;
        {
            float m0 = (l == 0) ? 0.f : a[0].x;
            float m1 = (l == 0) ? 0.f : a[1].x;
            float m2 = (l == 0) ? 0.f : a[2].x;
            float m3 = (l == 0) ? 0.f : a[3].x;
            s0 = m0 * m0 + a[0].y * a[0].y + a[0].z * a[0].z + a[0].w * a[0].w;
            s1 = m1 * m1 + a[1].y * a[1].y + a[1].z * a[1].z + a[1].w * a[1].w;
            s2 = m2 * m2 + a[2].y * a[2].y + a[2].z * a[2].z + a[2].w * a[2].w;
            s3 = m3 * m3 + a[3].y * a[3].y + a[3].z * a[3].z + a[3].w * a[3].w;
        }
        gsum16x4(s0, s1, s2, s3);
        float n2a[4] = {s0, s1, s2, s3};
#pragma unroll
        for (int p = 0; p < 4; p++) {
            float n2 = n2a[p];
            float n = fmaxf(sqrtf(n2), MIN_NORM);
            float th = fmaxf(sqrtf(1.f + n2), 1.f + EPS);
            float ac = __logf(th + sqrtf(fmaxf(th * th - 1.f, MIN_NORM)));
            float sc = ac * frcp(n);
            float ux0 = (l == 0) ? 0.f : sc * a[p].x;
            float uy = sc * a[p].y, uz = sc * a[p].z, uw = sc * a[p].w;
            unsigned short hx = f2bf(ux0), hy = f2bf(uy), hz = f2bf(uz), hw = f2bf(uw);
            ushort4 hv = {hx, hy, hz, hw};
            ushort4 lv = {f2bf(ux0 - bf2f(hx)), f2bf(uy - bf2f(hy)),
                          f2bf(uz - bf2f(hz)), f2bf(uw - bf2f(hw))};
            *(ushort4*)(uh + r * UPITCH + p * 64 + 4 * l) = hv;
            *(ushort4*)(ul + r * UPITCH + p * 64 + 4 * l) = lv;
        }
    }
    __syncthreads();

    // ---- MFMA GEMM: M=16, N=256 (wave wv: 4 n-tiles), K=256, split-bf16 3-term ----
    float4v acc[4];
#pragma unroll
    for (int j = 0; j < 4; j++) acc[j] = (float4v){0.f, 0.f, 0.f, 0.f};
    int abyte = (lane & 15) * (UPITCH * 2) + (lane >> 4) * 16;
#pragma unroll
    for (int ks = 0; ks < 8; ks++) {
        short8v Ah = *(const short8v*)(smem + abyte + ks * 64);
        short8v Al = *(const short8v*)(smem + 8448 + abyte + ks * 64);
#pragma unroll
        for (int j = 0; j < 4; j++) {
            size_t chunk = ((size_t)((wv * 4 + j) * 8 + ks) * 64 + lane) * 8;
            short8v Bh = *(const short8v*)(bhi + chunk);
            short8v Bl = *(const short8v*)(blo + chunk);
            acc[j] = __builtin_amdgcn_mfma_f32_16x16x32_bf16(Ah, Bh, acc[j], 0, 0, 0);
            acc[j] = __builtin_amdgcn_mfma_f32_16x16x32_bf16(Al, Bh, acc[j], 0, 0, 0);
            acc[j] = __builtin_amdgcn_mfma_f32_16x16x32_bf16(Ah, Bl, acc[j], 0, 0, 0);
        }
    }
    __syncthreads();  // A-reads done before aliasing LDS with mu

    // ---- D write, col-major (pitch 17 -> conflict-free) ----
#pragma unroll
    for (int j = 0; j < 4; j++) {
        int col = (wv * 4 + j) * 16 + (lane & 15);
        int rbase = (lane >> 4) * 4;
#pragma unroll
        for (int reg = 0; reg < 4; reg++) {
            mulds[col * DPITCH + rbase + reg] = acc[j][reg];
        }
    }
    __syncthreads();

    // ---- epilogue (transposed): thread (r, l); 4 points/thread ----
    {
        float m[4][4];   // [point][e]
        float uv[4][4];  // usp slices
        float n2p[4], dup[4];
#pragma unroll
        for (int p = 0; p < 4; p++) {
            float4 u4 = ((const float4*)uspL)[p * 16 + l];
            uv[p][0] = u4.x; uv[p][1] = u4.y; uv[p][2] = u4.z; uv[p][3] = u4.w;
            float pn = 0.f, pd = 0.f;
#pragma unroll
            for (int e = 0; e < 4; e++) {
                float mv = mulds[(p * 64 + 4 * l + e) * DPITCH + r];
                if (l == 0 && e == 0) mv = 0.f;   // mask time element
                m[p][e] = mv;
                pn = fmaf(mv, mv, pn);
                pd = fmaf(mv, uv[p][e], pd);
            }
            n2p[p] = pn; dup[p] = pd;
        }
        gsum16x4(n2p[0], n2p[1], n2p[2], n2p[3]);
        gsum16x4(dup[0], dup[1], dup[2], dup[3]);

#pragma unroll
        for (int p = 0; p < 4; p++) {
            float n2 = n2p[p], duu = dup[p], U2 = u2L[p];
            float n = fmaxf(sqrtf(n2), MIN_NORM);
            float ep = __expf(n), em = frcp(ep);
            float s = 0.5f * (ep - em) * frcp(n);       // sinh(n)/n
            float hs2 = s * s * n2;
            float h0 = sqrtf(fmaxf(1.f + hs2, EPS));
            float yn = fmaxf(s * n, MIN_NORM);
            float dhu = s * duu;
            float alpha = dhu * frcp(yn);
            float g = alpha * (1.f - h0);
            float ux = dhu - g * yn;
            float t = ux * frcp(fmaxf(h0, MIN_NORM));
            float w2 = U2 - 2.f * g * alpha + g * g;
            float md = w2 - t * t;
            float normu = fminf(sqrtf(fmaxf(md, EPS)), MAX_NORM);
            float theta = fmaxf(normu, MIN_NORM);
            float ep2 = __expf(theta), em2 = frcp(ep2);
            float ch = 0.5f * (ep2 + em2);
            float shot = 0.5f * (ep2 - em2) * frcp(theta);
            float rn2 = ch * ch * hs2 + 2.f * ch * shot * ux + shot * shot * w2;
            float rtime = sqrtf(fmaxf(1.f + rn2, EPS));
            float th2 = fmaxf(rtime, 1.f + EPS);
            float ac2 = __logf(th2 + sqrtf(fmaxf(th2 * th2 - 1.f, MIN_NORM)));
            float rn = fmaxf(sqrtf(rn2), MIN_NORM);
            float K = ac2 * frcp(rn);
            float A = K * s * (ch - shot * g * frcp(yn));  // coeff on mu_el
            float B = K * shot;                            // coeff on usp_el
            ushort4 ov;
            ov.x = f2bf(fmaf(A, m[p][0], B * uv[p][0]));
            ov.y = f2bf(fmaf(A, m[p][1], B * uv[p][1]));
            ov.z = f2bf(fmaf(A, m[p][2], B * uv[p][2]));
            ov.w = f2bf(fmaf(A, m[p][3], B * uv[p][3]));
            *(ushort4*)(xt + (size_t)(row0 + r) * 256 + p * 64 + 4 * l) = ov;
        }
    }
}

// ---------- CSR build ----------
__global__ void zero_kernel(int* __restrict__ p, int n) {
    int i = blockIdx.x * 256 + threadIdx.x;
    if (i < n) p[i] = 0;
}
__global__ void hist_kernel(const int* __restrict__ row, int* __restrict__ counts, int E) {
    int e = blockIdx.x * 256 + threadIdx.x;
    if (e < E) atomicAdd(&counts[row[e]], 1);
}

#define SCH 30
__global__ __launch_bounds__(1024) void scan_kernel(const int* __restrict__ counts,
                                                    int* __restrict__ starts, int n) {
    int tid = threadIdx.x, lane = tid & 63, wv = tid >> 6;
    int i0 = tid * SCH;
    int c[SCH];
    int s = 0;
#pragma unroll
    for (int j = 0; j < SCH; j++) {
        int idx = i0 + j;
        int v = (idx < n) ? counts[idx] : 0;
        c[j] = v;
        s += v;
    }
    int incl = s;
#pragma unroll
    for (int off = 1; off < 64; off <<= 1) {
        int t = __shfl_up(incl, off, 64);
        if (lane >= off) incl += t;
    }
    __shared__ int wtot[16];
    if (lane == 63) wtot[wv] = incl;
    __syncthreads();
    if (wv == 0 && lane < 16) {
        int v = wtot[lane];
        int sc = v;
#pragma unroll
        for (int off = 1; off < 16; off <<= 1) {
            int t = __shfl_up(sc, off, 64);
            if (lane >= off) sc += t;
        }
        wtot[lane] = sc - v;  // exclusive
    }
    __syncthreads();
    int run = incl - s + wtot[wv];
#pragma unroll
    for (int j = 0; j < SCH; j++) {
        int idx = i0 + j;
        if (idx < n) starts[idx] = run;
        run += c[j];
    }
    if (tid == 1023) starts[n] = run;
}

__global__ void scatter_kernel(const int* __restrict__ row, const int* __restrict__ col,
                               const float* __restrict__ val, const int* __restrict__ starts,
                               int* __restrict__ cursor, int* __restrict__ colp,
                               float* __restrict__ valp, int E) {
    int e = blockIdx.x * 256 + threadIdx.x;
    if (e < E) {
        int r = row[e];
        int pos = starts[r] + atomicAdd(&cursor[r], 1);
        colp[pos] = col[e];
        valp[pos] = val[e];
    }
}

// ---------- SpMM (wave/row, bf16 gather) + fused final chain ----------
__global__ __launch_bounds__(256) void spmm_final_kernel(const unsigned short* __restrict__ xt,
                                                         const int* __restrict__ colp,
                                                         const float* __restrict__ valp,
                                                         const int* __restrict__ starts,
                                                         float4* __restrict__ out4) {
    int w = threadIdx.x >> 6;
    int lane = threadIdx.x & 63;
    int r = blockIdx.x * 4 + w;
    int s = starts[r], e = starts[r + 1];

    float4 acc = {0.f, 0.f, 0.f, 0.f};
    int i = s;
    for (; i + 4 <= e; i += 4) {
        int c0 = colp[i], c1 = colp[i + 1], c2 = colp[i + 2], c3 = colp[i + 3];
        float v0 = valp[i], v1 = valp[i + 1], v2 = valp[i + 2], v3 = valp[i + 3];
        ushort4 a0 = *(const ushort4*)(xt + ((size_t)c0 << 8) + (lane << 2));
        ushort4 a1 = *(const ushort4*)(xt + ((size_t)c1 << 8) + (lane << 2));
        ushort4 a2 = *(const ushort4*)(xt + ((size_t)c2 << 8) + (lane << 2));
        ushort4 a3 = *(const ushort4*)(xt + ((size_t)c3 << 8) + (lane << 2));
        acc.x = fmaf(v0, bf2f(a0.x), acc.x); acc.y = fmaf(v0, bf2f(a0.y), acc.y);
        acc.z = fmaf(v0, bf2f(a0.z), acc.z); acc.w = fmaf(v0, bf2f(a0.w), acc.w);
        acc.x = fmaf(v1, bf2f(a1.x), acc.x); acc.y = fmaf(v1, bf2f(a1.y), acc.y);
        acc.z = fmaf(v1, bf2f(a1.z), acc.z); acc.w = fmaf(v1, bf2f(a1.w), acc.w);
        acc.x = fmaf(v2, bf2f(a2.x), acc.x); acc.y = fmaf(v2, bf2f(a2.y), acc.y);
        acc.z = fmaf(v2, bf2f(a2.z), acc.z); acc.w = fmaf(v2, bf2f(a2.w), acc.w);
        acc.x = fmaf(v3, bf2f(a3.x), acc.x); acc.y = fmaf(v3, bf2f(a3.y), acc.y);
        acc.z = fmaf(v3, bf2f(a3.z), acc.z); acc.w = fmaf(v3, bf2f(a3.w), acc.w);
    }
    for (; i < e; i++) {
        int c0 = colp[i];
        float v0 = valp[i];
        ushort4 a0 = *(const ushort4*)(xt + ((size_t)c0 << 8) + (lane << 2));
        acc.x = fmaf(v0, bf2f(a0.x), acc.x); acc.y = fmaf(v0, bf2f(a0.y), acc.y);
        acc.z = fmaf(v0, bf2f(a0.z), acc.z); acc.w = fmaf(v0, bf2f(a0.w), acc.w);
    }

    acc.x = fminf(acc.x, MAX_NORM); acc.y = fminf(acc.y, MAX_NORM);
    acc.z = fminf(acc.z, MAX_NORM); acc.w = fminf(acc.w, MAX_NORM);

    bool leader = ((lane & 15) == 0);
    float4 sp = acc;
    if (leader) sp.x = 0.f;
    float n2 = gsum16(sp.x * sp.x + sp.y * sp.y + sp.z * sp.z + sp.w * sp.w);
    float n = fmaxf(sqrtf(n2), MIN_NORM);
    float ep = __expf(n), em = frcp(ep);
    float s1 = 0.5f * (ep - em) * frcp(n);
    float hs2 = s1 * s1 * n2;
    float time = sqrtf(fmaxf(1.f + hs2, EPS));
    float th = fmaxf(time, 1.f + EPS);
    float ac = __logf(th + sqrtf(fmaxf(th * th - 1.f, MIN_NORM)));
    float hn = fmaxf(s1 * n, MIN_NORM);
    float sc = ac * s1 * frcp(hn);
    float4 t;
    t.x = leader ? 0.f : sc * sp.x;
    t.y = sc * sp.y;
    t.z = sc * sp.z;
    t.w = sc * sp.w;
    t.x = fminf(fmaxf(t.x, 0.f), MAX_NORM);
    t.y = fminf(fmaxf(t.y, 0.f), MAX_NORM);
    t.z = fminf(fmaxf(t.z, 0.f), MAX_NORM);
    t.w = fminf(fmaxf(t.w, 0.f), MAX_NORM);
    float t2 = gsum16(t.x * t.x + t.y * t.y + t.z * t.z + t.w * t.w);
    float nt = fmaxf(sqrtf(t2), MIN_NORM);
    float ep3 = __expf(nt), em3 = frcp(ep3);
    float s3 = 0.5f * (ep3 - em3) * frcp(nt);
    float time3 = sqrtf(fmaxf(1.f + s3 * s3 * t2, EPS));
    float4 o;
    o.x = leader ? time3 : s3 * t.x;
    o.y = s3 * t.y;
    o.z = s3 * t.z;
    o.w = s3 * t.w;

    out4[(size_t)r * 64 + lane] = o;
}

extern "C" void kernel_launch(void* const* d_in, const int* in_sizes, int n_in,
                              void* d_out, int out_size, void* d_ws, size_t ws_size,
                              hipStream_t stream) {
    const float* x       = (const float*)d_in[0];
    const float* adj_val = (const float*)d_in[1];
    const float* weight  = (const float*)d_in[2];
    const float* bias    = (const float*)d_in[3];
    const int*   adj_row = (const int*)d_in[4];
    const int*   adj_col = (const int*)d_in[5];

    const int N = NN, E = EE;

    unsigned short* B   = (unsigned short*)d_ws;          // N*256 bf16 (xt)
    unsigned short* Whi = B + (size_t)N * 256;            // 65536 ushort
    unsigned short* Wlo = Whi + 65536;                    // 65536 ushort
    int* counts  = (int*)(Wlo + 65536);                   // N
    int* cursor  = counts + N;                            // N
    int* starts  = cursor + N;                            // N+1
    int* colp    = starts + N + 1;                        // E
    float* valp  = (float*)(colp + E);                    // E

    pack_w_kernel<<<32, 256, 0, stream>>>(weight, Whi, Wlo);
    fused_front_kernel<<<N / GR, 256, 0, stream>>>(x, Whi, Wlo, bias, B);

    zero_kernel<<<(2 * N + 255) / 256, 256, 0, stream>>>(counts, 2 * N);
    hist_kernel<<<(E + 255) / 256, 256, 0, stream>>>(adj_row, counts, E);
    scan_kernel<<<1, 1024, 0, stream>>>(counts, starts, N);
    scatter_kernel<<<(E + 255) / 256, 256, 0, stream>>>(adj_row, adj_col, adj_val,
                                                        starts, cursor, colp, valp, E);

    spmm_final_kernel<<<N / 4, 256, 0, stream>>>(B, colp, valp, starts, (float4*)d_out);
}

// Round 7
// 146.500 us; speedup vs baseline: 4.1295x; 1.1389x over previous
//
#include <hip/hip_runtime.h>
#include <hip/hip_bf16.h>

#define MIN_NORM 1e-15f
#define EPS 1e-7f
#define MAX_NORM 1000.0f

#define NN 30000
#define PP 4
#define DD 64
#define EE 480000

typedef __attribute__((ext_vector_type(8))) short short8v;
typedef __attribute__((ext_vector_type(4))) float float4v;

__device__ inline float frcp(float x) { return __builtin_amdgcn_rcpf(x); }
__device__ inline float bf2f(unsigned short u) { return __uint_as_float(((unsigned)u) << 16); }
__device__ inline unsigned short f2bf(float f) {
    unsigned u = __float_as_uint(f);
    return (unsigned short)((u + 0x7fffu + ((u >> 16) & 1u)) >> 16);
}

// ---------- wave-wide helpers (bias stage only) ----------
__device__ inline float wsum(float v) {
#pragma unroll
    for (int off = 32; off >= 1; off >>= 1) v += __shfl_xor(v, off, 64);
    return v;
}
__device__ inline float expmap0_proj_pt(float v, int lane) {
    float sp = (lane == 0) ? 0.f : v;
    float n2 = wsum(sp * sp);
    float n = fmaxf(sqrtf(n2), MIN_NORM);
    float ep = __expf(n), em = frcp(ep);
    float s = 0.5f * (ep - em) * frcp(n);
    float time = sqrtf(fmaxf(1.f + s * s * n2, EPS));
    return (lane == 0) ? time : s * sp;
}
__device__ inline float logmap0_pt(float x, int lane) {
    float sp = (lane == 0) ? 0.f : x;
    float n2 = wsum(sp * sp);
    float n = fmaxf(sqrtf(n2), MIN_NORM);
    float x0 = __shfl(x, 0, 64);
    float th = fmaxf(x0, 1.f + EPS);
    float ac = __logf(th + sqrtf(fmaxf(th * th - 1.f, MIN_NORM)));
    return (lane == 0) ? 0.f : (ac * sp * frcp(n));
}
__device__ inline float gsum16(float v) {
#pragma unroll
    for (int off = 8; off >= 1; off >>= 1) v += __shfl_xor(v, off, 64);
    return v;
}
__device__ inline void gsum16x4(float& a, float& b, float& c, float& d) {
#pragma unroll
    for (int off = 8; off >= 1; off >>= 1) {
        a += __shfl_xor(a, off, 64);
        b += __shfl_xor(b, off, 64);
        c += __shfl_xor(c, off, 64);
        d += __shfl_xor(d, off, 64);
    }
}

// ---------- prep: pack W (MFMA B-frag order, split bf16 hi/lo) + zero counts/cursor ----------
__global__ void prep_kernel(const float* __restrict__ w,
                            unsigned short* __restrict__ bhi,
                            unsigned short* __restrict__ blo,
                            int* __restrict__ cz) {
    int b = blockIdx.x;
    if (b < 32) {
        int tt = b * 256 + threadIdx.x;  // [0, 8192)
        int lane = tt & 63;
        int ks = (tt >> 6) & 7;
        int nt = tt >> 9;
        int col = nt * 16 + (lane & 15);
        int kb = ks * 32 + (lane >> 4) * 8;
#pragma unroll
        for (int e = 0; e < 8; e++) {
            float v = w[col * 256 + kb + e];
            unsigned short h = f2bf(v);
            bhi[tt * 8 + e] = h;
            blo[tt * 8 + e] = f2bf(v - bf2f(h));
        }
    } else {
        int i = (b - 32) * 256 + threadIdx.x;
        if (i < 2 * NN) cz[i] = 0;
    }
}

// ---------- fused front (+ edge histogram riding in tail blocks) ----------
#define GR 16
#define UPITCH 264            // bf16 elems per row (528 B)
__global__ __launch_bounds__(256) void fused_front_hist_kernel(const float* __restrict__ x,
                                                               const unsigned short* __restrict__ bhi,
                                                               const unsigned short* __restrict__ blo,
                                                               const float* __restrict__ bias,
                                                               unsigned short* __restrict__ xt,
                                                               const int* __restrict__ adj_row,
                                                               int* __restrict__ counts,
                                                               int nFront) {
    __shared__ __align__(16) char smem[17952];

    if (blockIdx.x >= nFront) {  // histogram blocks
        int e = (blockIdx.x - nFront) * 256 + threadIdx.x;
        if (e < EE) atomicAdd(&counts[adj_row[e]], 1);
        return;
    }

    unsigned short* uh = (unsigned short*)smem;            // [16][264] bf16 hi
    unsigned short* ul = (unsigned short*)(smem + 8448);   // [16][264] bf16 lo
    float* uspL = (float*)(smem + 16896);                  // [256] bias tangent
    float* u2L  = (float*)(smem + 17920);                  // [4] ||usp||^2 per point

    int tid = threadIdx.x;
    int lane = tid & 63;
    int wv = tid >> 6;
    int row0 = blockIdx.x * GR;

    // ---- bias tangent (wave wv == point wv), staged to LDS ----
    {
        float b = bias[wv * 64 + lane];
        float y = expmap0_proj_pt(b, lane);
        float usp = logmap0_pt(y, lane);
        float U2 = wsum(usp * usp);
        uspL[wv * 64 + lane] = usp;
        if (lane == 0) u2L[wv] = U2;
    }

    // ---- prologue (transposed): thread (r = tid>>4, l = tid&15) ----
    int r = tid >> 4, l = tid & 15;
    {
        const float4* xr = (const float4*)(x + (size_t)(row0 + r) * 256);
        float4 a[4];
#pragma unroll
        for (int p = 0; p < 4; p++) a[p] = xr[p * 16 + l];
        float s0, s1, s2, s3;
        {
            float m0 = (l == 0) ? 0.f : a[0].x;
            float m1 = (l == 0) ? 0.f : a[1].x;
            float m2 = (l == 0) ? 0.f : a[2].x;
            float m3 = (l == 0) ? 0.f : a[3].x;
            s0 = m0 * m0 + a[0].y * a[0].y + a[0].z * a[0].z + a[0].w * a[0].w;
            s1 = m1 * m1 + a[1].y * a[1].y + a[1].z * a[1].z + a[1].w * a[1].w;
            s2 = m2 * m2 + a[2].y * a[2].y + a[2].z * a[2].z + a[2].w * a[2].w;
            s3 = m3 * m3 + a[3].y * a[3].y + a[3].z * a[3].z + a[3].w * a[3].w;
        }
        gsum16x4(s0, s1, s2, s3);
        float n2a[4] = {s0, s1, s2, s3};
#pragma unroll
        for (int p = 0; p < 4; p++) {
            float n2 = n2a[p];
            float n = fmaxf(sqrtf(n2), MIN_NORM);
            float th = fmaxf(sqrtf(1.f + n2), 1.f + EPS);
            float ac = __logf(th + sqrtf(fmaxf(th * th - 1.f, MIN_NORM)));
            float sc = ac * frcp(n);
            float ux0 = (l == 0) ? 0.f : sc * a[p].x;
            float uy = sc * a[p].y, uz = sc * a[p].z, uw = sc * a[p].w;
            unsigned short hx = f2bf(ux0), hy = f2bf(uy), hz = f2bf(uz), hw = f2bf(uw);
            ushort4 hv = {hx, hy, hz, hw};
            ushort4 lv = {f2bf(ux0 - bf2f(hx)), f2bf(uy - bf2f(hy)),
                          f2bf(uz - bf2f(hz)), f2bf(uw - bf2f(hw))};
            *(ushort4*)(uh + r * UPITCH + p * 64 + 4 * l) = hv;
            *(ushort4*)(ul + r * UPITCH + p * 64 + 4 * l) = lv;
        }
    }
    __syncthreads();  // the only barrier

    // ---- MFMA GEMM: M=16, N=256 (wave wv: 4 n-tiles), K=256, split-bf16 3-term ----
    float4v acc[4];
#pragma unroll
    for (int j = 0; j < 4; j++) acc[j] = (float4v){0.f, 0.f, 0.f, 0.f};
    int abyte = (lane & 15) * (UPITCH * 2) + (lane >> 4) * 16;
#pragma unroll
    for (int ks = 0; ks < 8; ks++) {
        short8v Ah = *(const short8v*)(smem + abyte + ks * 64);
        short8v Al = *(const short8v*)(smem + 8448 + abyte + ks * 64);
#pragma unroll
        for (int j = 0; j < 4; j++) {
            size_t chunk = ((size_t)((wv * 4 + j) * 8 + ks) * 64 + lane) * 8;
            short8v Bh = *(const short8v*)(bhi + chunk);
            short8v Bl = *(const short8v*)(blo + chunk);
            acc[j] = __builtin_amdgcn_mfma_f32_16x16x32_bf16(Ah, Bh, acc[j], 0, 0, 0);
            acc[j] = __builtin_amdgcn_mfma_f32_16x16x32_bf16(Al, Bh, acc[j], 0, 0, 0);
            acc[j] = __builtin_amdgcn_mfma_f32_16x16x32_bf16(Ah, Bl, acc[j], 0, 0, 0);
        }
    }

    // ---- epilogue directly from accumulators ----
    // D layout: col = (wv*4+j)*16 + (lane&15), row = (lane>>4)*4 + reg
    int lp = lane & 15, hi = lane >> 4;
    float uf[4];
#pragma unroll
    for (int j = 0; j < 4; j++) uf[j] = uspL[wv * 64 + j * 16 + lp];
    if (lp == 0) {  // mask the point's time element (global col d=0 -> j==0, lp==0)
        acc[0][0] = 0.f; acc[0][1] = 0.f; acc[0][2] = 0.f; acc[0][3] = 0.f;
    }
    float n2v[4], duv[4];
#pragma unroll
    for (int reg = 0; reg < 4; reg++) {
        float pn = 0.f, pd = 0.f;
#pragma unroll
        for (int j = 0; j < 4; j++) {
            pn = fmaf(acc[j][reg], acc[j][reg], pn);
            pd = fmaf(acc[j][reg], uf[j], pd);
        }
        n2v[reg] = pn; duv[reg] = pd;
    }
#pragma unroll
    for (int off = 1; off < 16; off <<= 1) {
#pragma unroll
        for (int reg = 0; reg < 4; reg++) {
            n2v[reg] += __shfl_xor(n2v[reg], off, 64);
            duv[reg] += __shfl_xor(duv[reg], off, 64);
        }
    }
    float U2 = u2L[wv];

    float A[4], Bc[4];
#pragma unroll
    for (int reg = 0; reg < 4; reg++) {
        float n2 = n2v[reg], duu = duv[reg];
        float n = fmaxf(sqrtf(n2), MIN_NORM);
        float epv = __expf(n), emv = frcp(epv);
        float sv = 0.5f * (epv - emv) * frcp(n);     // sinh(n)/n
        float hs2 = sv * sv * n2;
        float h0 = sqrtf(fmaxf(1.f + hs2, EPS));
        float yn = fmaxf(sv * n, MIN_NORM);
        float dhu = sv * duu;
        float alpha = dhu * frcp(yn);
        float g = alpha * (1.f - h0);
        float ux = dhu - g * yn;
        float t = ux * frcp(fmaxf(h0, MIN_NORM));
        float w2 = U2 - 2.f * g * alpha + g * g;
        float md = w2 - t * t;
        float normu = fminf(sqrtf(fmaxf(md, EPS)), MAX_NORM);
        float theta = fmaxf(normu, MIN_NORM);
        float ep2 = __expf(theta), em2 = frcp(ep2);
        float ch = 0.5f * (ep2 + em2);
        float shot = 0.5f * (ep2 - em2) * frcp(theta);
        float rn2 = ch * ch * hs2 + 2.f * ch * shot * ux + shot * shot * w2;
        float rtime = sqrtf(fmaxf(1.f + rn2, EPS));
        float th2 = fmaxf(rtime, 1.f + EPS);
        float ac2 = __logf(th2 + sqrtf(fmaxf(th2 * th2 - 1.f, MIN_NORM)));
        float rn = fmaxf(sqrtf(rn2), MIN_NORM);
        float K = ac2 * frcp(rn);
        A[reg] = K * sv * (ch - shot * g * frcp(yn));
        Bc[reg] = K * shot;
    }

    unsigned short* xbase = xt + (size_t)(row0 + hi * 4) * 256 + wv * 64 + lp;
#pragma unroll
    for (int reg = 0; reg < 4; reg++) {
#pragma unroll
        for (int j = 0; j < 4; j++) {
            float o = fmaf(A[reg], acc[j][reg], Bc[reg] * uf[j]);
            xbase[reg * 256 + j * 16] = f2bf(o);
        }
    }
}

// ---------- scan (single block, int4 loads) ----------
#define SCH 32
__global__ __launch_bounds__(1024) void scan_kernel(const int* __restrict__ counts,
                                                    int* __restrict__ starts, int n) {
    int tid = threadIdx.x, lane = tid & 63, wv = tid >> 6;
    int i0 = tid * SCH;
    int c[SCH];
    const int4* c4 = (const int4*)(counts + i0);
#pragma unroll
    for (int q = 0; q < 8; q++) {
        int4 v = c4[q];   // reads past n land in zeroed cursor region (safe, zero)
        c[4 * q] = v.x; c[4 * q + 1] = v.y; c[4 * q + 2] = v.z; c[4 * q + 3] = v.w;
    }
    int s = 0;
#pragma unroll
    for (int j = 0; j < SCH; j++) s += c[j];
    int incl = s;
#pragma unroll
    for (int off = 1; off < 64; off <<= 1) {
        int t = __shfl_up(incl, off, 64);
        if (lane >= off) incl += t;
    }
    __shared__ int wtot[16];
    if (lane == 63) wtot[wv] = incl;
    __syncthreads();
    if (wv == 0 && lane < 16) {
        int v = wtot[lane];
        int sc = v;
#pragma unroll
        for (int off = 1; off < 16; off <<= 1) {
            int t = __shfl_up(sc, off, 64);
            if (lane >= off) sc += t;
        }
        wtot[lane] = sc - v;  // exclusive
    }
    __syncthreads();
    int run = incl - s + wtot[wv];
#pragma unroll
    for (int j = 0; j < SCH; j++) {
        int idx = i0 + j;
        if (idx < n) starts[idx] = run;
        run += c[j];
    }
    if (tid == 1023) starts[n] = run;
}

// ---------- scatter: packed (col, val) per edge ----------
__global__ void scatter_kernel(const int* __restrict__ row, const int* __restrict__ col,
                               const float* __restrict__ val, const int* __restrict__ starts,
                               int* __restrict__ cursor, int2* __restrict__ ep, int E) {
    int e = blockIdx.x * 256 + threadIdx.x;
    if (e < E) {
        int r = row[e];
        int pos = starts[r] + atomicAdd(&cursor[r], 1);
        ep[pos] = make_int2(col[e], __float_as_int(val[e]));
    }
}

// ---------- SpMM (wave/row, predicated 8-wide batches) + fused final chain ----------
__global__ __launch_bounds__(256) void spmm_final_kernel(const unsigned short* __restrict__ xt,
                                                         const int2* __restrict__ ep,
                                                         const int* __restrict__ starts,
                                                         float4* __restrict__ out4) {
    int w = threadIdx.x >> 6;
    int lane = threadIdx.x & 63;
    int r = blockIdx.x * 4 + w;
    int s = starts[r], e = starts[r + 1];

    float4 acc = {0.f, 0.f, 0.f, 0.f};
    for (int i = s; i < e; i += 8) {
        int cs[8]; float vs[8];
#pragma unroll
        for (int u = 0; u < 8; u++) {
            int idx = i + u;
            bool ok = idx < e;
            int2 pe = ep[ok ? idx : s];
            cs[u] = pe.x;
            vs[u] = ok ? __int_as_float(pe.y) : 0.f;
        }
        ushort4 av[8];
#pragma unroll
        for (int u = 0; u < 8; u++)
            av[u] = *(const ushort4*)(xt + ((size_t)cs[u] << 8) + (lane << 2));
#pragma unroll
        for (int u = 0; u < 8; u++) {
            acc.x = fmaf(vs[u], bf2f(av[u].x), acc.x);
            acc.y = fmaf(vs[u], bf2f(av[u].y), acc.y);
            acc.z = fmaf(vs[u], bf2f(av[u].z), acc.z);
            acc.w = fmaf(vs[u], bf2f(av[u].w), acc.w);
        }
    }

    acc.x = fminf(acc.x, MAX_NORM); acc.y = fminf(acc.y, MAX_NORM);
    acc.z = fminf(acc.z, MAX_NORM); acc.w = fminf(acc.w, MAX_NORM);

    // final chain: expmap0+proj -> logmap0 -> relu/clamp -> expmap0+proj
    bool leader = ((lane & 15) == 0);
    float4 sp = acc;
    if (leader) sp.x = 0.f;
    float n2 = gsum16(sp.x * sp.x + sp.y * sp.y + sp.z * sp.z + sp.w * sp.w);
    float n = fmaxf(sqrtf(n2), MIN_NORM);
    float ep1 = __expf(n), em1 = frcp(ep1);
    float s1 = 0.5f * (ep1 - em1) * frcp(n);
    float hs2 = s1 * s1 * n2;
    float time = sqrtf(fmaxf(1.f + hs2, EPS));
    float th = fmaxf(time, 1.f + EPS);
    float ac = __logf(th + sqrtf(fmaxf(th * th - 1.f, MIN_NORM)));
    float hn = fmaxf(s1 * n, MIN_NORM);
    float sc = ac * s1 * frcp(hn);
    float4 t;
    t.x = leader ? 0.f : sc * sp.x;
    t.y = sc * sp.y;
    t.z = sc * sp.z;
    t.w = sc * sp.w;
    t.x = fminf(fmaxf(t.x, 0.f), MAX_NORM);
    t.y = fminf(fmaxf(t.y, 0.f), MAX_NORM);
    t.z = fminf(fmaxf(t.z, 0.f), MAX_NORM);
    t.w = fminf(fmaxf(t.w, 0.f), MAX_NORM);
    float t2 = gsum16(t.x * t.x + t.y * t.y + t.z * t.z + t.w * t.w);
    float nt = fmaxf(sqrtf(t2), MIN_NORM);
    float ep3 = __expf(nt), em3 = frcp(ep3);
    float s3 = 0.5f * (ep3 - em3) * frcp(nt);
    float time3 = sqrtf(fmaxf(1.f + s3 * s3 * t2, EPS));
    float4 o;
    o.x = leader ? time3 : s3 * t.x;
    o.y = s3 * t.y;
    o.z = s3 * t.z;
    o.w = s3 * t.w;

    out4[(size_t)r * 64 + lane] = o;
}

extern "C" void kernel_launch(void* const* d_in, const int* in_sizes, int n_in,
                              void* d_out, int out_size, void* d_ws, size_t ws_size,
                              hipStream_t stream) {
    const float* x       = (const float*)d_in[0];
    const float* adj_val = (const float*)d_in[1];
    const float* weight  = (const float*)d_in[2];
    const float* bias    = (const float*)d_in[3];
    const int*   adj_row = (const int*)d_in[4];
    const int*   adj_col = (const int*)d_in[5];

    const int N = NN, E = EE;

    unsigned short* B   = (unsigned short*)d_ws;          // N*256 bf16 (xt)
    unsigned short* Whi = B + (size_t)N * 256;            // 65536 ushort
    unsigned short* Wlo = Whi + 65536;                    // 65536 ushort
    int* counts  = (int*)(Wlo + 65536);                   // N   (16B-aligned)
    int* cursor  = counts + N;                            // N
    int* starts  = cursor + N;                            // N+1 (+1 pad for int2 align)
    int2* ep     = (int2*)(starts + N + 2);               // E   (8B-aligned)

    const int nFront = N / GR;          // 1875
    const int nHist  = (E + 255) / 256; // 1875

    prep_kernel<<<32 + (2 * N + 255) / 256, 256, 0, stream>>>(weight, Whi, Wlo, counts);
    fused_front_hist_kernel<<<nFront + nHist, 256, 0, stream>>>(x, Whi, Wlo, bias, B,
                                                                adj_row, counts, nFront);
    scan_kernel<<<1, 1024, 0, stream>>>(counts, starts, N);
    scatter_kernel<<<(E + 255) / 256, 256, 0, stream>>>(adj_row, adj_col, adj_val,
                                                        starts, cursor, ep, E);
    spmm_final_kernel<<<N / 4, 256, 0, stream>>>(B, ep, starts, (float4*)d_out);
}

// Round 8
// 146.421 us; speedup vs baseline: 4.1317x; 1.0005x over previous
//
#include <hip/hip_runtime.h>
#include <hip/hip_bf16.h>

#define MIN_NORM 1e-15f
#define EPS 1e-7f
#define MAX_NORM 1000.0f

#define NN 30000
#define PP 4
#define DD 64
#define EE 480000

typedef __attribute__((ext_vector_type(8))) short short8v;
typedef __attribute__((ext_vector_type(4))) float float4v;

__device__ inline float frcp(float x) { return __builtin_amdgcn_rcpf(x); }
__device__ inline float bf2f(unsigned short u) { return __uint_as_float(((unsigned)u) << 16); }
__device__ inline unsigned short f2bf(float f) {
    unsigned u = __float_as_uint(f);
    return (unsigned short)((u + 0x7fffu + ((u >> 16) & 1u)) >> 16);
}

// ---------- wave-wide helpers (bias stage only) ----------
__device__ inline float wsum(float v) {
#pragma unroll
    for (int off = 32; off >= 1; off >>= 1) v += __shfl_xor(v, off, 64);
    return v;
}
__device__ inline float expmap0_proj_pt(float v, int lane) {
    float sp = (lane == 0) ? 0.f : v;
    float n2 = wsum(sp * sp);
    float n = fmaxf(sqrtf(n2), MIN_NORM);
    float ep = __expf(n), em = frcp(ep);
    float s = 0.5f * (ep - em) * frcp(n);
    float time = sqrtf(fmaxf(1.f + s * s * n2, EPS));
    return (lane == 0) ? time : s * sp;
}
__device__ inline float logmap0_pt(float x, int lane) {
    float sp = (lane == 0) ? 0.f : x;
    float n2 = wsum(sp * sp);
    float n = fmaxf(sqrtf(n2), MIN_NORM);
    float x0 = __shfl(x, 0, 64);
    float th = fmaxf(x0, 1.f + EPS);
    float ac = __logf(th + sqrtf(fmaxf(th * th - 1.f, MIN_NORM)));
    return (lane == 0) ? 0.f : (ac * sp * frcp(n));
}
__device__ inline float gsum16(float v) {
#pragma unroll
    for (int off = 8; off >= 1; off >>= 1) v += __shfl_xor(v, off, 64);
    return v;
}
__device__ inline void gsum16x4(float& a, float& b, float& c, float& d) {
#pragma unroll
    for (int off = 8; off >= 1; off >>= 1) {
        a += __shfl_xor(a, off, 64);
        b += __shfl_xor(b, off, 64);
        c += __shfl_xor(c, off, 64);
        d += __shfl_xor(d, off, 64);
    }
}

// ---------- prep: pack W (MFMA B-frag order, split bf16 hi/lo) + zero counts/cursor ----------
__global__ void prep_kernel(const float* __restrict__ w,
                            unsigned short* __restrict__ bhi,
                            unsigned short* __restrict__ blo,
                            int* __restrict__ cz) {
    int b = blockIdx.x;
    if (b < 32) {
        int tt = b * 256 + threadIdx.x;  // [0, 8192)
        int lane = tt & 63;
        int ks = (tt >> 6) & 7;
        int nt = tt >> 9;
        int col = nt * 16 + (lane & 15);
        int kb = ks * 32 + (lane >> 4) * 8;
#pragma unroll
        for (int e = 0; e < 8; e++) {
            float v = w[col * 256 + kb + e];
            unsigned short h = f2bf(v);
            bhi[tt * 8 + e] = h;
            blo[tt * 8 + e] = f2bf(v - bf2f(h));
        }
    } else {
        int i = (b - 32) * 256 + threadIdx.x;
        if (i < 2 * NN) cz[i] = 0;
    }
}

// ---------- fused front (GR=48) + fire-and-forget edge histogram ----------
#define GR 48
#define UPITCH 264            // bf16 elems per row (528 B)
#define EPB 768               // edges histogrammed per front block (625*768 = 480000)
__global__ __launch_bounds__(256) void fused_front_hist_kernel(const float* __restrict__ x,
                                                               const unsigned short* __restrict__ bhi,
                                                               const unsigned short* __restrict__ blo,
                                                               const float* __restrict__ bias,
                                                               unsigned short* __restrict__ xt,
                                                               const int* __restrict__ adj_row,
                                                               int* __restrict__ counts) {
    __shared__ __align__(16) char smem[51744];
    unsigned short* uh = (unsigned short*)smem;             // [48][264] bf16 hi
    unsigned short* ul = (unsigned short*)(smem + 25344);   // [48][264] bf16 lo
    float* uspL = (float*)(smem + 50688);                   // [256] bias tangent
    float* u2L  = (float*)(smem + 51712);                   // [4] ||usp||^2

    int tid = threadIdx.x;
    int lane = tid & 63;
    int wv = tid >> 6;
    int fb = blockIdx.x;
    int row0 = fb * GR;

    // ---- fire-and-forget histogram (no return value -> no wait until kernel end) ----
    {
        int e0 = fb * EPB + tid;
#pragma unroll
        for (int q = 0; q < 3; q++) atomicAdd(&counts[adj_row[e0 + q * 256]], 1);
    }

    // ---- bias tangent (wave wv == point wv), staged to LDS ----
    {
        float b = bias[wv * 64 + lane];
        float y = expmap0_proj_pt(b, lane);
        float usp = logmap0_pt(y, lane);
        float U2 = wsum(usp * usp);
        uspL[wv * 64 + lane] = usp;
        if (lane == 0) u2L[wv] = U2;
    }

    // ---- prologue (transposed): thread (r = tid>>4, l = tid&15); 3 row-chunks ----
    int r = tid >> 4, l = tid & 15;
    {
        float4 a[3][4];
#pragma unroll
        for (int rr = 0; rr < 3; rr++) {
            const float4* xr = (const float4*)(x + (size_t)(row0 + rr * 16 + r) * 256);
#pragma unroll
            for (int p = 0; p < 4; p++) a[rr][p] = xr[p * 16 + l];
        }
#pragma unroll
        for (int rr = 0; rr < 3; rr++) {
            float s0, s1, s2, s3;
            {
                float m0 = (l == 0) ? 0.f : a[rr][0].x;
                float m1 = (l == 0) ? 0.f : a[rr][1].x;
                float m2 = (l == 0) ? 0.f : a[rr][2].x;
                float m3 = (l == 0) ? 0.f : a[rr][3].x;
                s0 = m0 * m0 + a[rr][0].y * a[rr][0].y + a[rr][0].z * a[rr][0].z + a[rr][0].w * a[rr][0].w;
                s1 = m1 * m1 + a[rr][1].y * a[rr][1].y + a[rr][1].z * a[rr][1].z + a[rr][1].w * a[rr][1].w;
                s2 = m2 * m2 + a[rr][2].y * a[rr][2].y + a[rr][2].z * a[rr][2].z + a[rr][2].w * a[rr][2].w;
                s3 = m3 * m3 + a[rr][3].y * a[rr][3].y + a[rr][3].z * a[rr][3].z + a[rr][3].w * a[rr][3].w;
            }
            gsum16x4(s0, s1, s2, s3);
            float n2a[4] = {s0, s1, s2, s3};
            int rowbase = (rr * 16 + r) * UPITCH;
#pragma unroll
            for (int p = 0; p < 4; p++) {
                float n2 = n2a[p];
                float n = fmaxf(sqrtf(n2), MIN_NORM);
                float th = fmaxf(sqrtf(1.f + n2), 1.f + EPS);
                float ac = __logf(th + sqrtf(fmaxf(th * th - 1.f, MIN_NORM)));
                float sc = ac * frcp(n);
                float ux0 = (l == 0) ? 0.f : sc * a[rr][p].x;
                float uy = sc * a[rr][p].y, uz = sc * a[rr][p].z, uw = sc * a[rr][p].w;
                unsigned short hx = f2bf(ux0), hy = f2bf(uy), hz = f2bf(uz), hw = f2bf(uw);
                ushort4 hv = {hx, hy, hz, hw};
                ushort4 lv = {f2bf(ux0 - bf2f(hx)), f2bf(uy - bf2f(hy)),
                              f2bf(uz - bf2f(hz)), f2bf(uw - bf2f(hw))};
                *(ushort4*)(uh + rowbase + p * 64 + 4 * l) = hv;
                *(ushort4*)(ul + rowbase + p * 64 + 4 * l) = lv;
            }
        }
    }
    __syncthreads();  // the only barrier

    // ---- MFMA GEMM: M=48 (3 m-tiles), N=256 (wave wv: 4 n-tiles), K=256, split-bf16 ----
    float4v acc[3][4];
#pragma unroll
    for (int m = 0; m < 3; m++)
#pragma unroll
        for (int j = 0; j < 4; j++) acc[m][j] = (float4v){0.f, 0.f, 0.f, 0.f};
    int abyte = (lane & 15) * (UPITCH * 2) + (lane >> 4) * 16;
#pragma unroll
    for (int ks = 0; ks < 8; ks++) {
        short8v Ah[3], Al[3];
#pragma unroll
        for (int m = 0; m < 3; m++) {
            Ah[m] = *(const short8v*)(smem + abyte + m * 8448 + ks * 64);
            Al[m] = *(const short8v*)(smem + 25344 + abyte + m * 8448 + ks * 64);
        }
#pragma unroll
        for (int j = 0; j < 4; j++) {
            size_t chunk = ((size_t)((wv * 4 + j) * 8 + ks) * 64 + lane) * 8;
            short8v Bh = *(const short8v*)(bhi + chunk);
            short8v Bl = *(const short8v*)(blo + chunk);
#pragma unroll
            for (int m = 0; m < 3; m++) {
                acc[m][j] = __builtin_amdgcn_mfma_f32_16x16x32_bf16(Ah[m], Bh, acc[m][j], 0, 0, 0);
                acc[m][j] = __builtin_amdgcn_mfma_f32_16x16x32_bf16(Al[m], Bh, acc[m][j], 0, 0, 0);
                acc[m][j] = __builtin_amdgcn_mfma_f32_16x16x32_bf16(Ah[m], Bl, acc[m][j], 0, 0, 0);
            }
        }
    }

    // ---- epilogue directly from accumulators, per m-tile ----
    // D layout: col = (wv*4+j)*16 + (lane&15), row = m*16 + (lane>>4)*4 + reg
    int lp = lane & 15, hi = lane >> 4;
    float uf[4];
#pragma unroll
    for (int j = 0; j < 4; j++) uf[j] = uspL[wv * 64 + j * 16 + lp];
    float U2 = u2L[wv];

#pragma unroll
    for (int m = 0; m < 3; m++) {
        if (lp == 0) {  // mask point's time element (col = wv*64)
            acc[m][0][0] = 0.f; acc[m][0][1] = 0.f; acc[m][0][2] = 0.f; acc[m][0][3] = 0.f;
        }
        float n2v[4], duv[4];
#pragma unroll
        for (int reg = 0; reg < 4; reg++) {
            float pn = 0.f, pd = 0.f;
#pragma unroll
            for (int j = 0; j < 4; j++) {
                pn = fmaf(acc[m][j][reg], acc[m][j][reg], pn);
                pd = fmaf(acc[m][j][reg], uf[j], pd);
            }
            n2v[reg] = pn; duv[reg] = pd;
        }
#pragma unroll
        for (int off = 1; off < 16; off <<= 1) {
#pragma unroll
            for (int reg = 0; reg < 4; reg++) {
                n2v[reg] += __shfl_xor(n2v[reg], off, 64);
                duv[reg] += __shfl_xor(duv[reg], off, 64);
            }
        }
        float A[4], Bc[4];
#pragma unroll
        for (int reg = 0; reg < 4; reg++) {
            float n2 = n2v[reg], duu = duv[reg];
            float n = fmaxf(sqrtf(n2), MIN_NORM);
            float epv = __expf(n), emv = frcp(epv);
            float sv = 0.5f * (epv - emv) * frcp(n);     // sinh(n)/n
            float hs2 = sv * sv * n2;
            float h0 = sqrtf(fmaxf(1.f + hs2, EPS));
            float yn = fmaxf(sv * n, MIN_NORM);
            float dhu = sv * duu;
            float alpha = dhu * frcp(yn);
            float g = alpha * (1.f - h0);
            float ux = dhu - g * yn;
            float t = ux * frcp(fmaxf(h0, MIN_NORM));
            float w2 = U2 - 2.f * g * alpha + g * g;
            float md = w2 - t * t;
            float normu = fminf(sqrtf(fmaxf(md, EPS)), MAX_NORM);
            float theta = fmaxf(normu, MIN_NORM);
            float ep2 = __expf(theta), em2 = frcp(ep2);
            float ch = 0.5f * (ep2 + em2);
            float shot = 0.5f * (ep2 - em2) * frcp(theta);
            float rn2 = ch * ch * hs2 + 2.f * ch * shot * ux + shot * shot * w2;
            float rtime = sqrtf(fmaxf(1.f + rn2, EPS));
            float th2 = fmaxf(rtime, 1.f + EPS);
            float ac2 = __logf(th2 + sqrtf(fmaxf(th2 * th2 - 1.f, MIN_NORM)));
            float rn = fmaxf(sqrtf(rn2), MIN_NORM);
            float K = ac2 * frcp(rn);
            A[reg] = K * sv * (ch - shot * g * frcp(yn));
            Bc[reg] = K * shot;
        }
        unsigned short* xbase = xt + (size_t)(row0 + m * 16 + hi * 4) * 256 + wv * 64 + lp;
#pragma unroll
        for (int reg = 0; reg < 4; reg++) {
#pragma unroll
            for (int j = 0; j < 4; j++) {
                float o = fmaf(A[reg], acc[m][j][reg], Bc[reg] * uf[j]);
                xbase[reg * 256 + j * 16] = f2bf(o);
            }
        }
    }
}

// ---------- scan (single block, int4 loads) ----------
#define SCH 32
__global__ __launch_bounds__(1024) void scan_kernel(const int* __restrict__ counts,
                                                    int* __restrict__ starts, int n) {
    int tid = threadIdx.x, lane = tid & 63, wv = tid >> 6;
    int i0 = tid * SCH;
    int c[SCH];
    const int4* c4 = (const int4*)(counts + i0);
#pragma unroll
    for (int q = 0; q < 8; q++) {
        int4 v = c4[q];   // reads past n land in zeroed cursor region (safe, zero)
        c[4 * q] = v.x; c[4 * q + 1] = v.y; c[4 * q + 2] = v.z; c[4 * q + 3] = v.w;
    }
    int s = 0;
#pragma unroll
    for (int j = 0; j < SCH; j++) s += c[j];
    int incl = s;
#pragma unroll
    for (int off = 1; off < 64; off <<= 1) {
        int t = __shfl_up(incl, off, 64);
        if (lane >= off) incl += t;
    }
    __shared__ int wtot[16];
    if (lane == 63) wtot[wv] = incl;
    __syncthreads();
    if (wv == 0 && lane < 16) {
        int v = wtot[lane];
        int sc = v;
#pragma unroll
        for (int off = 1; off < 16; off <<= 1) {
            int t = __shfl_up(sc, off, 64);
            if (lane >= off) sc += t;
        }
        wtot[lane] = sc - v;  // exclusive
    }
    __syncthreads();
    int run = incl - s + wtot[wv];
#pragma unroll
    for (int j = 0; j < SCH; j++) {
        int idx = i0 + j;
        if (idx < n) starts[idx] = run;
        run += c[j];
    }
    if (tid == 1023) starts[n] = run;
}

// ---------- scatter: packed (col, val) per edge ----------
__global__ void scatter_kernel(const int* __restrict__ row, const int* __restrict__ col,
                               const float* __restrict__ val, const int* __restrict__ starts,
                               int* __restrict__ cursor, int2* __restrict__ ep, int E) {
    int e = blockIdx.x * 256 + threadIdx.x;
    if (e < E) {
        int r = row[e];
        int pos = starts[r] + atomicAdd(&cursor[r], 1);
        ep[pos] = make_int2(col[e], __float_as_int(val[e]));
    }
}

// ---------- SpMM (wave/row, predicated 8-wide batches) + fused final chain ----------
__global__ __launch_bounds__(256) void spmm_final_kernel(const unsigned short* __restrict__ xt,
                                                         const int2* __restrict__ ep,
                                                         const int* __restrict__ starts,
                                                         float4* __restrict__ out4) {
    int w = threadIdx.x >> 6;
    int lane = threadIdx.x & 63;
    int r = blockIdx.x * 4 + w;
    int s = starts[r], e = starts[r + 1];

    float4 acc = {0.f, 0.f, 0.f, 0.f};
    for (int i = s; i < e; i += 8) {
        int cs[8]; float vs[8];
#pragma unroll
        for (int u = 0; u < 8; u++) {
            int idx = i + u;
            bool ok = idx < e;
            int2 pe = ep[ok ? idx : s];
            cs[u] = pe.x;
            vs[u] = ok ? __int_as_float(pe.y) : 0.f;
        }
        ushort4 av[8];
#pragma unroll
        for (int u = 0; u < 8; u++)
            av[u] = *(const ushort4*)(xt + ((size_t)cs[u] << 8) + (lane << 2));
#pragma unroll
        for (int u = 0; u < 8; u++) {
            acc.x = fmaf(vs[u], bf2f(av[u].x), acc.x);
            acc.y = fmaf(vs[u], bf2f(av[u].y), acc.y);
            acc.z = fmaf(vs[u], bf2f(av[u].z), acc.z);
            acc.w = fmaf(vs[u], bf2f(av[u].w), acc.w);
        }
    }

    acc.x = fminf(acc.x, MAX_NORM); acc.y = fminf(acc.y, MAX_NORM);
    acc.z = fminf(acc.z, MAX_NORM); acc.w = fminf(acc.w, MAX_NORM);

    // final chain: expmap0+proj -> logmap0 -> relu/clamp -> expmap0+proj
    bool leader = ((lane & 15) == 0);
    float4 sp = acc;
    if (leader) sp.x = 0.f;
    float n2 = gsum16(sp.x * sp.x + sp.y * sp.y + sp.z * sp.z + sp.w * sp.w);
    float n = fmaxf(sqrtf(n2), MIN_NORM);
    float ep1 = __expf(n), em1 = frcp(ep1);
    float s1 = 0.5f * (ep1 - em1) * frcp(n);
    float hs2 = s1 * s1 * n2;
    float time = sqrtf(fmaxf(1.f + hs2, EPS));
    float th = fmaxf(time, 1.f + EPS);
    float ac = __logf(th + sqrtf(fmaxf(th * th - 1.f, MIN_NORM)));
    float hn = fmaxf(s1 * n, MIN_NORM);
    float sc = ac * s1 * frcp(hn);
    float4 t;
    t.x = leader ? 0.f : sc * sp.x;
    t.y = sc * sp.y;
    t.z = sc * sp.z;
    t.w = sc * sp.w;
    t.x = fminf(fmaxf(t.x, 0.f), MAX_NORM);
    t.y = fminf(fmaxf(t.y, 0.f), MAX_NORM);
    t.z = fminf(fmaxf(t.z, 0.f), MAX_NORM);
    t.w = fminf(fmaxf(t.w, 0.f), MAX_NORM);
    float t2 = gsum16(t.x * t.x + t.y * t.y + t.z * t.z + t.w * t.w);
    float nt = fmaxf(sqrtf(t2), MIN_NORM);
    float ep3 = __expf(nt), em3 = frcp(ep3);
    float s3 = 0.5f * (ep3 - em3) * frcp(nt);
    float time3 = sqrtf(fmaxf(1.f + s3 * s3 * t2, EPS));
    float4 o;
    o.x = leader ? time3 : s3 * t.x;
    o.y = s3 * t.y;
    o.z = s3 * t.z;
    o.w = s3 * t.w;

    out4[(size_t)r * 64 + lane] = o;
}

extern "C" void kernel_launch(void* const* d_in, const int* in_sizes, int n_in,
                              void* d_out, int out_size, void* d_ws, size_t ws_size,
                              hipStream_t stream) {
    const float* x       = (const float*)d_in[0];
    const float* adj_val = (const float*)d_in[1];
    const float* weight  = (const float*)d_in[2];
    const float* bias    = (const float*)d_in[3];
    const int*   adj_row = (const int*)d_in[4];
    const int*   adj_col = (const int*)d_in[5];

    const int N = NN, E = EE;

    unsigned short* B   = (unsigned short*)d_ws;          // N*256 bf16 (xt)
    unsigned short* Whi = B + (size_t)N * 256;            // 65536 ushort
    unsigned short* Wlo = Whi + 65536;                    // 65536 ushort
    int* counts  = (int*)(Wlo + 65536);                   // N   (16B-aligned)
    int* cursor  = counts + N;                            // N
    int* starts  = cursor + N;                            // N+1 (+1 pad for int2 align)
    int2* ep     = (int2*)(starts + N + 2);               // E   (8B-aligned)

    prep_kernel<<<32 + (2 * N + 255) / 256, 256, 0, stream>>>(weight, Whi, Wlo, counts);
    fused_front_hist_kernel<<<N / GR, 256, 0, stream>>>(x, Whi, Wlo, bias, B,
                                                        adj_row, counts);
    scan_kernel<<<1, 1024, 0, stream>>>(counts, starts, N);
    scatter_kernel<<<(E + 255) / 256, 256, 0, stream>>>(adj_row, adj_col, adj_val,
                                                        starts, cursor, ep, E);
    spmm_final_kernel<<<N / 4, 256, 0, stream>>>(B, ep, starts, (float4*)d_out);
}